// Round 1
// baseline (1988.897 us; speedup 1.0000x reference)
//
#include <hip/hip_runtime.h>
#include <cstdint>
#include <cstddef>

typedef short short8 __attribute__((ext_vector_type(8)));
typedef float f32x4 __attribute__((ext_vector_type(4)));

#define B_   8
#define N_   4096
#define S_   1024
#define K_   16
#define M_   131072   /* B*S*K */
#define CIN_ 64

__device__ inline float bf2f(unsigned short u) {
    unsigned int v = ((unsigned int)u) << 16;
    return __builtin_bit_cast(float, v);
}
__device__ inline unsigned short f2bf(float f) {
    unsigned int u = __builtin_bit_cast(unsigned int, f);
    unsigned int lsb = (u >> 16) & 1u;
    u += 0x7fffu + lsb;
    return (unsigned short)(u >> 16);
}

// ---------------- FPS: one block per batch, sequential 1024 steps ----------------
__global__ __launch_bounds__(512) void fps_kernel(const float* __restrict__ xyz,
                                                  float* __restrict__ outxyz)
{
    int b = blockIdx.x;
    const float* xb = xyz + (size_t)b * N_ * 3;
    float* ob = outxyz + (size_t)b * S_ * 3;
    int t = threadIdx.x;
    const int NP = N_ / 512; // 8
    float px[NP], py[NP], pz[NP], dst[NP];
#pragma unroll
    for (int i = 0; i < NP; i++) {
        int p = i * 512 + t;
        px[i] = xb[p * 3 + 0];
        py[i] = xb[p * 3 + 1];
        pz[i] = xb[p * 3 + 2];
        dst[i] = 1e10f;
    }
    __shared__ float sd[2][8];
    __shared__ int   sp[2][8];
    int far = 0;
    int w = t >> 6, l = t & 63;
    for (int s = 0; s < S_; s++) {
        float cx = xb[far * 3 + 0], cy = xb[far * 3 + 1], cz = xb[far * 3 + 2];
        if (t == 0) { ob[s * 3 + 0] = cx; ob[s * 3 + 1] = cy; ob[s * 3 + 2] = cz; }
        float bd = -1.0f; int bp = 0;
#pragma unroll
        for (int i = 0; i < NP; i++) {
            // replicate ref: sum((p-c)^2) with plain mul/add (no FMA contraction)
            float dx = __fsub_rn(px[i], cx);
            float dy = __fsub_rn(py[i], cy);
            float dz = __fsub_rn(pz[i], cz);
            float d  = __fadd_rn(__fadd_rn(__fmul_rn(dx, dx), __fmul_rn(dy, dy)),
                                 __fmul_rn(dz, dz));
            float nd = fminf(dst[i], d);
            dst[i] = nd;
            if (nd > bd) { bd = nd; bp = i * 512 + t; }
        }
#pragma unroll
        for (int off = 32; off >= 1; off >>= 1) {
            float od = __shfl_xor(bd, off);
            int   op = __shfl_xor(bp, off);
            if (od > bd || (od == bd && op < bp)) { bd = od; bp = op; }
        }
        int par = s & 1;
        if (l == 0) { sd[par][w] = bd; sp[par][w] = bp; }
        __syncthreads();
        float gbd = sd[par][0]; int gbp = sp[par][0];
#pragma unroll
        for (int j = 1; j < 8; j++) {
            float od = sd[par][j]; int op = sp[par][j];
            if (od > gbd || (od == gbd && op < gbp)) { gbd = od; gbp = op; }
        }
        far = gbp;
    }
}

// ---------------- per-point squared norm (exact ref formula) ----------------
__global__ void sqn_kernel(const float* __restrict__ xyz, float* __restrict__ sqn)
{
    int i = blockIdx.x * 256 + threadIdx.x;
    if (i >= B_ * N_) return;
    float x = xyz[i * 3 + 0], y = xyz[i * 3 + 1], z = xyz[i * 3 + 2];
    sqn[i] = __fadd_rn(__fadd_rn(__fmul_rn(x, x), __fmul_rn(y, y)), __fmul_rn(z, z));
}

// ---------------- kNN: one wave per query ----------------
__global__ __launch_bounds__(256) void knn_kernel(const float* __restrict__ xyz,
                                                  const float* __restrict__ sqn,
                                                  const float* __restrict__ newxyz,
                                                  int* __restrict__ idx)
{
    int w = threadIdx.x >> 6, l = threadIdx.x & 63;
    int q = blockIdx.x * 4 + w;          // 0..8191
    int b = q >> 10;
    const float* xb = xyz + (size_t)b * N_ * 3;
    const float* sb = sqn + (size_t)b * N_;
    float qx = newxyz[(size_t)q * 3 + 0];
    float qy = newxyz[(size_t)q * 3 + 1];
    float qz = newxyz[(size_t)q * 3 + 2];
    float sa = __fadd_rn(__fadd_rn(__fmul_rn(qx, qx), __fmul_rn(qy, qy)), __fmul_rn(qz, qz));

    float d16[16]; int i16[16];
#pragma unroll
    for (int j = 0; j < 16; j++) { d16[j] = 3.0e38f; i16[j] = -1; }
    // d16 kept descending: d16[0] = current worst, d16[15] = best
    for (int i = 0; i < N_ / 64; i++) {
        int n = i * 64 + l;
        float bx = xb[n * 3 + 0], by = xb[n * 3 + 1], bz = xb[n * 3 + 2];
        float dot = __fmaf_rn(qz, bz, __fmaf_rn(qy, by, __fmul_rn(qx, bx)));
        float d = __fsub_rn(__fadd_rn(sa, sb[n]), __fmul_rn(2.0f, dot));
        if (d < d16[0]) {   // strict: equal keeps older (lower) index, matches stable top_k
            d16[0] = d; i16[0] = n;
#pragma unroll
            for (int j = 0; j < 15; j++) {
                if (d16[j] < d16[j + 1]) {
                    float td = d16[j]; d16[j] = d16[j + 1]; d16[j + 1] = td;
                    int   ti = i16[j]; i16[j] = i16[j + 1]; i16[j + 1] = ti;
                }
            }
        }
    }
    int* iq = idx + (size_t)q * 16;
#pragma unroll
    for (int r = 0; r < 16; r++) {
        float cd = d16[15]; int cn = i16[15];
#pragma unroll
        for (int off = 1; off < 64; off <<= 1) {
            float od = __shfl_xor(cd, off);
            int   on = __shfl_xor(cn, off);
            if (od < cd || (od == cd && on < cn)) { cd = od; cn = on; }
        }
        if (l == 0) iq[r] = cn;
        if (i16[15] == cn) {   // winner pops (n unique across lanes)
#pragma unroll
            for (int j = 15; j >= 1; j--) { d16[j] = d16[j - 1]; i16[j] = i16[j - 1]; }
            d16[0] = 3.0e38f; i16[0] = -1;
        }
    }
}

// ---------------- build X = [grouped_xyz_norm | grouped_pts | 0pad] (bf16) ----------------
__global__ void build_x(const float* __restrict__ xyz, const float* __restrict__ pts,
                        const float* __restrict__ newxyz, const int* __restrict__ idx,
                        unsigned short* __restrict__ X)
{
    size_t tid = (size_t)blockIdx.x * 256 + threadIdx.x;
    if (tid >= (size_t)M_ * 96) return;
    int c = (int)(tid % 96);
    size_t r = tid / 96;
    int s = (int)((r >> 4) & 1023);
    int b = (int)(r >> 14);
    int n = idx[r];
    float v;
    if (c < 3)      v = xyz[((size_t)b * N_ + n) * 3 + c] - newxyz[((size_t)b * S_ + s) * 3 + c];
    else if (c < 67) v = pts[((size_t)b * N_ + n) * CIN_ + (c - 3)];
    else             v = 0.0f;
    X[tid] = f2bf(v);
}

// ---------------- weight prep: transpose + pad to bf16 [Nrows][KPAD] ----------------
__global__ void fill_wt(unsigned short* __restrict__ dst, const float* __restrict__ src,
                        int Kreal, int Nrows, int Nsrc, int KPAD)
{
    int tid = blockIdx.x * 256 + threadIdx.x;
    if (tid >= Nrows * KPAD) return;
    int row = tid / KPAD, k = tid % KPAD;
    float v = (k < Kreal && row < Nsrc) ? src[(size_t)k * Nsrc + row] : 0.0f;
    dst[tid] = f2bf(v);
}

// ---------------- MFMA GEMM with fused BN-stat accumulation ----------------
template<int KPAD, int NF>
__global__ __launch_bounds__(256) void gemm_bn(
    const unsigned short* __restrict__ A, const unsigned short* __restrict__ Wt,
    unsigned short* __restrict__ Z1, int ld1, int n1real, float* sum1, float* sq1,
    unsigned short* __restrict__ Z2, int ld2, int n2real, float* sum2, float* sq2,
    int split)
{
    __shared__ unsigned short sA[128 * KPAD];
    __shared__ float sSt[NF * 32];
    int t = threadIdx.x;
    int r0 = blockIdx.x * 128;
    for (int i = t; i < NF * 32; i += 256) sSt[i] = 0.0f;
    {
        const uint4* ga = (const uint4*)(A + (size_t)r0 * KPAD);
        uint4* la = (uint4*)sA;
        const int CNT = 128 * KPAD * 2 / 16;
        for (int i = t; i < CNT; i += 256) la[i] = ga[i];
    }
    __syncthreads();
    int w = t >> 6, l = t & 63, lhi = l >> 4, llo = l & 15;
    f32x4 acc[2][NF];
#pragma unroll
    for (int m = 0; m < 2; m++)
#pragma unroll
        for (int n = 0; n < NF; n++) acc[m][n] = (f32x4){0.f, 0.f, 0.f, 0.f};
#pragma unroll
    for (int ks = 0; ks < KPAD / 32; ks++) {
        short8 bfr[NF];
#pragma unroll
        for (int n = 0; n < NF; n++)
            bfr[n] = *(const short8*)(Wt + (size_t)(n * 16 + llo) * KPAD + ks * 32 + lhi * 8);
#pragma unroll
        for (int m = 0; m < 2; m++) {
            short8 afr = *(const short8*)(sA + (w * 32 + m * 16 + llo) * KPAD + ks * 32 + lhi * 8);
#pragma unroll
            for (int n = 0; n < NF; n++)
                acc[m][n] = __builtin_amdgcn_mfma_f32_16x16x32_bf16(afr, bfr[n], acc[m][n], 0, 0, 0);
        }
    }
#pragma unroll
    for (int n = 0; n < NF; n++) {
        int c = n * 16 + llo;
        float ss = 0.f, sq = 0.f;
#pragma unroll
        for (int m = 0; m < 2; m++) {
#pragma unroll
            for (int j = 0; j < 4; j++) {
                float v = acc[m][n][j];
                int row = r0 + w * 32 + m * 16 + lhi * 4 + j;
                unsigned short hv = f2bf(v);
                if (c < split) Z1[(size_t)row * ld1 + c] = hv;
                else           Z2[(size_t)row * ld2 + (c - split)] = hv;
                ss += v; sq += v * v;
            }
        }
        ss += __shfl_xor(ss, 16); ss += __shfl_xor(ss, 32);
        sq += __shfl_xor(sq, 16); sq += __shfl_xor(sq, 32);
        if (l < 16) { atomicAdd(&sSt[c * 2], ss); atomicAdd(&sSt[c * 2 + 1], sq); }
    }
    __syncthreads();
    for (int c = t; c < NF * 16; c += 256) {
        float ss = sSt[c * 2], sq = sSt[c * 2 + 1];
        if (c < split) {
            if (c < n1real) { atomicAdd(&sum1[c], ss); atomicAdd(&sq1[c], sq); }
        } else {
            int cc = c - split;
            if (cc < n2real) { atomicAdd(&sum2[cc], ss); atomicAdd(&sq2[cc], sq); }
        }
    }
}

// ---------------- BN finalize: a = g*rsqrt(var+eps), c = b - a*mean ----------------
__global__ void bn_finalize(const float* __restrict__ sum, const float* __restrict__ sq,
                            const float* __restrict__ g, const float* __restrict__ bb,
                            float* __restrict__ a, float* __restrict__ c, int n)
{
    int i = blockIdx.x * 256 + threadIdx.x;
    if (i >= n) return;
    const float inv = 1.0f / (float)M_;
    float m = sum[i] * inv;
    float var = sq[i] * inv - m * m;
    float av = g[i] * rsqrtf(var + 1e-5f);
    a[i] = av;
    c[i] = bb[i] - av * m;
}

// ---------------- normalize + relu + repad ----------------
__global__ void norm_relu(const unsigned short* __restrict__ Z, int zld, int nreal,
                          unsigned short* __restrict__ H, int hld,
                          const float* __restrict__ a, const float* __restrict__ c,
                          size_t total)
{
    size_t tid = (size_t)blockIdx.x * 256 + threadIdx.x;
    if (tid >= total) return;
    int col = (int)(tid % hld);
    size_t r = tid / hld;
    float v = 0.0f;
    if (col < nreal) v = fmaxf(a[col] * bf2f(Z[r * zld + col]) + c[col], 0.0f);
    H[r * hld + col] = f2bf(v);
}

// ---------------- final: bn3(z3)+bnsc(zsc), relu, max over K ----------------
__global__ void final_kernel(const unsigned short* __restrict__ Z3,
                             const unsigned short* __restrict__ ZSC,
                             const float* __restrict__ a3, const float* __restrict__ c3,
                             const float* __restrict__ asc, const float* __restrict__ csc,
                             float* __restrict__ out)
{
    int tid = blockIdx.x * 256 + threadIdx.x;  // 8192*128
    int ch = tid & 127, bs = tid >> 7;
    float A3 = a3[ch], C3 = c3[ch], AS = asc[ch], CS = csc[ch];
    float mx = 0.0f;
    for (int k = 0; k < 16; k++) {
        size_t row = (size_t)bs * 16 + k;
        float v3 = bf2f(Z3[row * 128 + ch]);
        float vs = bf2f(ZSC[row * 128 + ch]);
        float y = fmaxf(A3 * v3 + C3 + AS * vs + CS, 0.0f);
        mx = fmaxf(mx, y);
    }
    out[24576 + (size_t)bs * 128 + ch] = mx;
}

// ---------------- workspace layout (bytes) ----------------
#define WS_STATS 0
#define WS_WT1   16384
#define WS_WT2   68608
#define WS_WT3   114688
#define WS_SQN   155648
#define WS_IDX   286720
#define WS_X     811008
#define WS_Z     25976832
#define WS_ZSC   63725568
#define WS_H     97280000

extern "C" void kernel_launch(void* const* d_in, const int* in_sizes, int n_in,
                              void* d_out, int out_size, void* d_ws, size_t ws_size,
                              hipStream_t stream)
{
    const float* xyz    = (const float*)d_in[0];
    const float* pts    = (const float*)d_in[1];
    const float* fc1_w  = (const float*)d_in[2];
    const float* bn1_g  = (const float*)d_in[4];
    const float* bn1_b  = (const float*)d_in[5];
    const float* fc2_w  = (const float*)d_in[6];
    const float* bn2_g  = (const float*)d_in[8];
    const float* bn2_b  = (const float*)d_in[9];
    const float* fc3_w  = (const float*)d_in[10];
    const float* bn3_g  = (const float*)d_in[12];
    const float* bn3_b  = (const float*)d_in[13];
    const float* sc_w   = (const float*)d_in[14];
    const float* scbn_g = (const float*)d_in[16];
    const float* scbn_b = (const float*)d_in[17];

    char* ws = (char*)d_ws;
    float* st = (float*)(ws + WS_STATS);
    float* bn1_sum = st + 0,    *bn1_sq = st + 134;
    float* bnsc_sum = st + 268, *bnsc_sq = st + 396;
    float* bn2_sum = st + 524,  *bn2_sq = st + 658;
    float* bn3_sum = st + 792,  *bn3_sq = st + 920;
    float* a1 = st + 1048, *c1 = st + 1182;
    float* a2 = st + 1316, *c2 = st + 1450;
    float* a3 = st + 1584, *c3 = st + 1712;
    float* asc = st + 1840, *csc = st + 1968;

    unsigned short* WT1 = (unsigned short*)(ws + WS_WT1);
    unsigned short* WT2 = (unsigned short*)(ws + WS_WT2);
    unsigned short* WT3 = (unsigned short*)(ws + WS_WT3);
    float* SQN = (float*)(ws + WS_SQN);
    int*   IDX = (int*)(ws + WS_IDX);
    unsigned short* X   = (unsigned short*)(ws + WS_X);
    unsigned short* Z   = (unsigned short*)(ws + WS_Z);
    unsigned short* ZSC = (unsigned short*)(ws + WS_ZSC);
    unsigned short* H   = (unsigned short*)(ws + WS_H);
    float* out = (float*)d_out;

    hipMemsetAsync(ws + WS_STATS, 0, 1048 * 4, stream);

    fill_wt<<<54, 256, 0, stream>>>(WT1, fc1_w, 67, 144, 134, 96);
    fill_wt<<<48, 256, 0, stream>>>(WT1 + 144 * 96, sc_w, 67, 128, 128, 96);
    fill_wt<<<90, 256, 0, stream>>>(WT2, fc2_w, 134, 144, 134, 160);
    fill_wt<<<80, 256, 0, stream>>>(WT3, fc3_w, 134, 128, 128, 160);

    fps_kernel<<<8, 512, 0, stream>>>(xyz, out);
    sqn_kernel<<<128, 256, 0, stream>>>(xyz, SQN);
    knn_kernel<<<2048, 256, 0, stream>>>(xyz, SQN, out, IDX);
    build_x<<<49152, 256, 0, stream>>>(xyz, pts, out, IDX, X);

    // GEMM1 fused with shortcut GEMM: X[M,96] @ Wt[272,96]^T -> z1 (134 of 144) | zsc (128)
    gemm_bn<96, 17><<<1024, 256, 0, stream>>>(X, WT1,
        Z, 144, 134, bn1_sum, bn1_sq,
        ZSC, 128, 128, bnsc_sum, bnsc_sq, 144);
    bn_finalize<<<1, 256, 0, stream>>>(bn1_sum, bn1_sq, bn1_g, bn1_b, a1, c1, 134);
    bn_finalize<<<1, 256, 0, stream>>>(bnsc_sum, bnsc_sq, scbn_g, scbn_b, asc, csc, 128);
    norm_relu<<<81920, 256, 0, stream>>>(Z, 144, 134, H, 160, a1, c1, (size_t)M_ * 160);

    gemm_bn<160, 9><<<1024, 256, 0, stream>>>(H, WT2,
        Z, 144, 134, bn2_sum, bn2_sq,
        Z, 144, 0, bn2_sum, bn2_sq, 144);
    bn_finalize<<<1, 256, 0, stream>>>(bn2_sum, bn2_sq, bn2_g, bn2_b, a2, c2, 134);
    norm_relu<<<81920, 256, 0, stream>>>(Z, 144, 134, H, 160, a2, c2, (size_t)M_ * 160);

    gemm_bn<160, 8><<<1024, 256, 0, stream>>>(H, WT3,
        Z, 128, 128, bn3_sum, bn3_sq,
        Z, 128, 0, bn3_sum, bn3_sq, 128);
    bn_finalize<<<1, 256, 0, stream>>>(bn3_sum, bn3_sq, bn3_g, bn3_b, a3, c3, 128);

    final_kernel<<<4096, 256, 0, stream>>>(Z, ZSC, a3, c3, asc, csc, out);
}

// Round 2
// 1139.289 us; speedup vs baseline: 1.7457x; 1.7457x over previous
//
#include <hip/hip_runtime.h>
#include <cstdint>
#include <cstddef>

typedef short short8 __attribute__((ext_vector_type(8)));
typedef float f32x4 __attribute__((ext_vector_type(4)));

#define B_   8
#define N_   4096
#define S_   1024
#define K_   16
#define M_   131072   /* B*S*K */
#define CIN_ 64

__device__ inline float bf2f(unsigned short u) {
    unsigned int v = ((unsigned int)u) << 16;
    return __builtin_bit_cast(float, v);
}
__device__ inline unsigned short f2bf(float f) {
    unsigned int u = __builtin_bit_cast(unsigned int, f);
    unsigned int lsb = (u >> 16) & 1u;
    u += 0x7fffu + lsb;
    return (unsigned short)(u >> 16);
}

// ---------------- FPS helpers: packed-key max reductions ----------------
template<int CTRL>
__device__ inline unsigned long long dpp_max(unsigned long long k) {
    unsigned lo = (unsigned)k, hi = (unsigned)(k >> 32);
    unsigned olo = (unsigned)__builtin_amdgcn_update_dpp(0, (int)lo, CTRL, 0xF, 0xF, true);
    unsigned ohi = (unsigned)__builtin_amdgcn_update_dpp(0, (int)hi, CTRL, 0xF, 0xF, true);
    unsigned long long ok = ((unsigned long long)ohi << 32) | (unsigned long long)olo;
    return ok > k ? ok : k;
}
__device__ inline unsigned long long swz16_max(unsigned long long k) {
    unsigned lo = (unsigned)k, hi = (unsigned)(k >> 32);
    unsigned olo = (unsigned)__builtin_amdgcn_ds_swizzle((int)lo, 0x401F); // lane ^= 16
    unsigned ohi = (unsigned)__builtin_amdgcn_ds_swizzle((int)hi, 0x401F);
    unsigned long long ok = ((unsigned long long)ohi << 32) | (unsigned long long)olo;
    return ok > k ? ok : k;
}
__device__ inline unsigned long long shf32_max(unsigned long long k) {
    unsigned lo = (unsigned)k, hi = (unsigned)(k >> 32);
    unsigned olo = (unsigned)__shfl_xor((int)lo, 32);
    unsigned ohi = (unsigned)__shfl_xor((int)hi, 32);
    unsigned long long ok = ((unsigned long long)ohi << 32) | (unsigned long long)olo;
    return ok > k ? ok : k;
}

// ---------------- FPS: one block per batch, sequential 1024 steps ----------------
// 256 threads (4 waves, 1 wave/SIMD). Points pinned in VGPRs; LDS mirror for
// centroid lookup; NO global memory ops inside the step loop (barrier waits
// only on LDS). One barrier per step, parity-double-buffered 4-key combine.
__global__ __launch_bounds__(256) void fps_kernel(const float* __restrict__ xyz,
                                                  float* __restrict__ outxyz)
{
    __shared__ float px_s[N_], py_s[N_], pz_s[N_];   // 48 KB point mirror
    __shared__ float sOut[S_ * 3];                   // 12 KB output staging
    __shared__ unsigned long long sK[2][4];
    int b = blockIdx.x;
    const float* xb = xyz + (size_t)b * N_ * 3;
    int t = threadIdx.x;
    int w = t >> 6, l = t & 63;
    const int NP = 16;
    float px[NP], py[NP], pz[NP], dst[NP];
#pragma unroll
    for (int i = 0; i < NP; i++) {
        int p = i * 256 + t;
        px[i] = xb[p * 3 + 0];
        py[i] = xb[p * 3 + 1];
        pz[i] = xb[p * 3 + 2];
        dst[i] = 1e10f;
        px_s[p] = px[i]; py_s[p] = py[i]; pz_s[p] = pz[i];
        asm volatile("" : "+v"(px[i]), "+v"(py[i]), "+v"(pz[i]));  // pin in VGPRs (defeat remat)
    }
    __syncthreads();
    float cx = px_s[0], cy = py_s[0], cz = pz_s[0];  // far = 0 deterministic start
    for (int s = 0; s < S_; s++) {
        if (t == 0) { sOut[s * 3 + 0] = cx; sOut[s * 3 + 1] = cy; sOut[s * 3 + 2] = cz; }
        if (s == S_ - 1) break;
        float bd = -1.0f; int bp = 0;
#pragma unroll
        for (int i = 0; i < NP; i++) {
            // exact ref semantics: plain mul/add, no FMA contraction
            float dx = __fsub_rn(px[i], cx);
            float dy = __fsub_rn(py[i], cy);
            float dz = __fsub_rn(pz[i], cz);
            float d  = __fadd_rn(__fadd_rn(__fmul_rn(dx, dx), __fmul_rn(dy, dy)),
                                 __fmul_rn(dz, dz));
            float nd = fminf(dst[i], d);
            dst[i] = nd;
            if (nd > bd) { bd = nd; bp = i * 256 + t; }  // strict >: lowest i on tie
        }
        // pack: d >= 0 so float bits are order-preserving; (4095-idx) => tie -> lowest idx
        unsigned long long key =
            ((unsigned long long)__builtin_bit_cast(unsigned, bd) << 32) |
            (unsigned long long)(unsigned)(4095 - bp);
        key = dpp_max<0xB1>(key);   // quad_perm [1,0,3,2]  : lane ^ 1
        key = dpp_max<0x4E>(key);   // quad_perm [2,3,0,1]  : lane ^ 2
        key = dpp_max<0x141>(key);  // row_half_mirror      : lane ^ 7
        key = dpp_max<0x140>(key);  // row_mirror           : lane ^ 15
        key = swz16_max(key);       // ds_swizzle           : lane ^ 16
        key = shf32_max(key);       // shfl                 : lane ^ 32
        int par = s & 1;
        if (l == 0) sK[par][w] = key;
        __syncthreads();
        unsigned long long k0 = sK[par][0], k1 = sK[par][1];
        unsigned long long k2 = sK[par][2], k3 = sK[par][3];
        unsigned long long ka = k0 > k1 ? k0 : k1;
        unsigned long long kb = k2 > k3 ? k2 : k3;
        unsigned long long g  = ka > kb ? ka : kb;
        int p = 4095 - (int)(g & 0xFFFu);
        cx = px_s[p]; cy = py_s[p]; cz = pz_s[p];    // LDS broadcast (same addr all lanes)
    }
    __syncthreads();
    float* ob = outxyz + (size_t)b * S_ * 3;
    for (int i = t; i < S_ * 3; i += 256) ob[i] = sOut[i];
}

// ---------------- per-point squared norm (exact ref formula) ----------------
__global__ void sqn_kernel(const float* __restrict__ xyz, float* __restrict__ sqn)
{
    int i = blockIdx.x * 256 + threadIdx.x;
    if (i >= B_ * N_) return;
    float x = xyz[i * 3 + 0], y = xyz[i * 3 + 1], z = xyz[i * 3 + 2];
    sqn[i] = __fadd_rn(__fadd_rn(__fmul_rn(x, x), __fmul_rn(y, y)), __fmul_rn(z, z));
}

// ---------------- kNN: one wave per query ----------------
__global__ __launch_bounds__(256) void knn_kernel(const float* __restrict__ xyz,
                                                  const float* __restrict__ sqn,
                                                  const float* __restrict__ newxyz,
                                                  int* __restrict__ idx)
{
    int w = threadIdx.x >> 6, l = threadIdx.x & 63;
    int q = blockIdx.x * 4 + w;          // 0..8191
    int b = q >> 10;
    const float* xb = xyz + (size_t)b * N_ * 3;
    const float* sb = sqn + (size_t)b * N_;
    float qx = newxyz[(size_t)q * 3 + 0];
    float qy = newxyz[(size_t)q * 3 + 1];
    float qz = newxyz[(size_t)q * 3 + 2];
    float sa = __fadd_rn(__fadd_rn(__fmul_rn(qx, qx), __fmul_rn(qy, qy)), __fmul_rn(qz, qz));

    float d16[16]; int i16[16];
#pragma unroll
    for (int j = 0; j < 16; j++) { d16[j] = 3.0e38f; i16[j] = -1; }
    // d16 kept descending: d16[0] = current worst, d16[15] = best
    for (int i = 0; i < N_ / 64; i++) {
        int n = i * 64 + l;
        float bx = xb[n * 3 + 0], by = xb[n * 3 + 1], bz = xb[n * 3 + 2];
        float dot = __fmaf_rn(qz, bz, __fmaf_rn(qy, by, __fmul_rn(qx, bx)));
        float d = __fsub_rn(__fadd_rn(sa, sb[n]), __fmul_rn(2.0f, dot));
        if (d < d16[0]) {   // strict: equal keeps older (lower) index, matches stable top_k
            d16[0] = d; i16[0] = n;
#pragma unroll
            for (int j = 0; j < 15; j++) {
                if (d16[j] < d16[j + 1]) {
                    float td = d16[j]; d16[j] = d16[j + 1]; d16[j + 1] = td;
                    int   ti = i16[j]; i16[j] = i16[j + 1]; i16[j + 1] = ti;
                }
            }
        }
    }
    int* iq = idx + (size_t)q * 16;
#pragma unroll
    for (int r = 0; r < 16; r++) {
        float cd = d16[15]; int cn = i16[15];
#pragma unroll
        for (int off = 1; off < 64; off <<= 1) {
            float od = __shfl_xor(cd, off);
            int   on = __shfl_xor(cn, off);
            if (od < cd || (od == cd && on < cn)) { cd = od; cn = on; }
        }
        if (l == 0) iq[r] = cn;
        if (i16[15] == cn) {   // winner pops (n unique across lanes)
#pragma unroll
            for (int j = 15; j >= 1; j--) { d16[j] = d16[j - 1]; i16[j] = i16[j - 1]; }
            d16[0] = 3.0e38f; i16[0] = -1;
        }
    }
}

// ---------------- build X = [grouped_xyz_norm | grouped_pts | 0pad] (bf16) ----------------
__global__ void build_x(const float* __restrict__ xyz, const float* __restrict__ pts,
                        const float* __restrict__ newxyz, const int* __restrict__ idx,
                        unsigned short* __restrict__ X)
{
    size_t tid = (size_t)blockIdx.x * 256 + threadIdx.x;
    if (tid >= (size_t)M_ * 96) return;
    int c = (int)(tid % 96);
    size_t r = tid / 96;
    int s = (int)((r >> 4) & 1023);
    int b = (int)(r >> 14);
    int n = idx[r];
    float v;
    if (c < 3)      v = xyz[((size_t)b * N_ + n) * 3 + c] - newxyz[((size_t)b * S_ + s) * 3 + c];
    else if (c < 67) v = pts[((size_t)b * N_ + n) * CIN_ + (c - 3)];
    else             v = 0.0f;
    X[tid] = f2bf(v);
}

// ---------------- weight prep: transpose + pad to bf16 [Nrows][KPAD] ----------------
__global__ void fill_wt(unsigned short* __restrict__ dst, const float* __restrict__ src,
                        int Kreal, int Nrows, int Nsrc, int KPAD)
{
    int tid = blockIdx.x * 256 + threadIdx.x;
    if (tid >= Nrows * KPAD) return;
    int row = tid / KPAD, k = tid % KPAD;
    float v = (k < Kreal && row < Nsrc) ? src[(size_t)k * Nsrc + row] : 0.0f;
    dst[tid] = f2bf(v);
}

// ---------------- MFMA GEMM with fused BN-stat accumulation ----------------
template<int KPAD, int NF>
__global__ __launch_bounds__(256) void gemm_bn(
    const unsigned short* __restrict__ A, const unsigned short* __restrict__ Wt,
    unsigned short* __restrict__ Z1, int ld1, int n1real, float* sum1, float* sq1,
    unsigned short* __restrict__ Z2, int ld2, int n2real, float* sum2, float* sq2,
    int split)
{
    __shared__ unsigned short sA[128 * KPAD];
    __shared__ float sSt[NF * 32];
    int t = threadIdx.x;
    int r0 = blockIdx.x * 128;
    for (int i = t; i < NF * 32; i += 256) sSt[i] = 0.0f;
    {
        const uint4* ga = (const uint4*)(A + (size_t)r0 * KPAD);
        uint4* la = (uint4*)sA;
        const int CNT = 128 * KPAD * 2 / 16;
        for (int i = t; i < CNT; i += 256) la[i] = ga[i];
    }
    __syncthreads();
    int w = t >> 6, l = t & 63, lhi = l >> 4, llo = l & 15;
    f32x4 acc[2][NF];
#pragma unroll
    for (int m = 0; m < 2; m++)
#pragma unroll
        for (int n = 0; n < NF; n++) acc[m][n] = (f32x4){0.f, 0.f, 0.f, 0.f};
#pragma unroll
    for (int ks = 0; ks < KPAD / 32; ks++) {
        short8 bfr[NF];
#pragma unroll
        for (int n = 0; n < NF; n++)
            bfr[n] = *(const short8*)(Wt + (size_t)(n * 16 + llo) * KPAD + ks * 32 + lhi * 8);
#pragma unroll
        for (int m = 0; m < 2; m++) {
            short8 afr = *(const short8*)(sA + (w * 32 + m * 16 + llo) * KPAD + ks * 32 + lhi * 8);
#pragma unroll
            for (int n = 0; n < NF; n++)
                acc[m][n] = __builtin_amdgcn_mfma_f32_16x16x32_bf16(afr, bfr[n], acc[m][n], 0, 0, 0);
        }
    }
#pragma unroll
    for (int n = 0; n < NF; n++) {
        int c = n * 16 + llo;
        float ss = 0.f, sq = 0.f;
#pragma unroll
        for (int m = 0; m < 2; m++) {
#pragma unroll
            for (int j = 0; j < 4; j++) {
                float v = acc[m][n][j];
                int row = r0 + w * 32 + m * 16 + lhi * 4 + j;
                unsigned short hv = f2bf(v);
                if (c < split) Z1[(size_t)row * ld1 + c] = hv;
                else           Z2[(size_t)row * ld2 + (c - split)] = hv;
                ss += v; sq += v * v;
            }
        }
        ss += __shfl_xor(ss, 16); ss += __shfl_xor(ss, 32);
        sq += __shfl_xor(sq, 16); sq += __shfl_xor(sq, 32);
        if (l < 16) { atomicAdd(&sSt[c * 2], ss); atomicAdd(&sSt[c * 2 + 1], sq); }
    }
    __syncthreads();
    for (int c = t; c < NF * 16; c += 256) {
        float ss = sSt[c * 2], sq = sSt[c * 2 + 1];
        if (c < split) {
            if (c < n1real) { atomicAdd(&sum1[c], ss); atomicAdd(&sq1[c], sq); }
        } else {
            int cc = c - split;
            if (cc < n2real) { atomicAdd(&sum2[cc], ss); atomicAdd(&sq2[cc], sq); }
        }
    }
}

// ---------------- BN finalize: a = g*rsqrt(var+eps), c = b - a*mean ----------------
__global__ void bn_finalize(const float* __restrict__ sum, const float* __restrict__ sq,
                            const float* __restrict__ g, const float* __restrict__ bb,
                            float* __restrict__ a, float* __restrict__ c, int n)
{
    int i = blockIdx.x * 256 + threadIdx.x;
    if (i >= n) return;
    const float inv = 1.0f / (float)M_;
    float m = sum[i] * inv;
    float var = sq[i] * inv - m * m;
    float av = g[i] * rsqrtf(var + 1e-5f);
    a[i] = av;
    c[i] = bb[i] - av * m;
}

// ---------------- normalize + relu + repad ----------------
__global__ void norm_relu(const unsigned short* __restrict__ Z, int zld, int nreal,
                          unsigned short* __restrict__ H, int hld,
                          const float* __restrict__ a, const float* __restrict__ c,
                          size_t total)
{
    size_t tid = (size_t)blockIdx.x * 256 + threadIdx.x;
    if (tid >= total) return;
    int col = (int)(tid % hld);
    size_t r = tid / hld;
    float v = 0.0f;
    if (col < nreal) v = fmaxf(a[col] * bf2f(Z[r * zld + col]) + c[col], 0.0f);
    H[r * hld + col] = f2bf(v);
}

// ---------------- final: bn3(z3)+bnsc(zsc), relu, max over K ----------------
__global__ void final_kernel(const unsigned short* __restrict__ Z3,
                             const unsigned short* __restrict__ ZSC,
                             const float* __restrict__ a3, const float* __restrict__ c3,
                             const float* __restrict__ asc, const float* __restrict__ csc,
                             float* __restrict__ out)
{
    int tid = blockIdx.x * 256 + threadIdx.x;  // 8192*128
    int ch = tid & 127, bs = tid >> 7;
    float A3 = a3[ch], C3 = c3[ch], AS = asc[ch], CS = csc[ch];
    float mx = 0.0f;
    for (int k = 0; k < 16; k++) {
        size_t row = (size_t)bs * 16 + k;
        float v3 = bf2f(Z3[row * 128 + ch]);
        float vs = bf2f(ZSC[row * 128 + ch]);
        float y = fmaxf(A3 * v3 + C3 + AS * vs + CS, 0.0f);
        mx = fmaxf(mx, y);
    }
    out[24576 + (size_t)bs * 128 + ch] = mx;
}

// ---------------- workspace layout (bytes) ----------------
#define WS_STATS 0
#define WS_WT1   16384
#define WS_WT2   68608
#define WS_WT3   114688
#define WS_SQN   155648
#define WS_IDX   286720
#define WS_X     811008
#define WS_Z     25976832
#define WS_ZSC   63725568
#define WS_H     97280000

extern "C" void kernel_launch(void* const* d_in, const int* in_sizes, int n_in,
                              void* d_out, int out_size, void* d_ws, size_t ws_size,
                              hipStream_t stream)
{
    const float* xyz    = (const float*)d_in[0];
    const float* pts    = (const float*)d_in[1];
    const float* fc1_w  = (const float*)d_in[2];
    const float* bn1_g  = (const float*)d_in[4];
    const float* bn1_b  = (const float*)d_in[5];
    const float* fc2_w  = (const float*)d_in[6];
    const float* bn2_g  = (const float*)d_in[8];
    const float* bn2_b  = (const float*)d_in[9];
    const float* fc3_w  = (const float*)d_in[10];
    const float* bn3_g  = (const float*)d_in[12];
    const float* bn3_b  = (const float*)d_in[13];
    const float* sc_w   = (const float*)d_in[14];
    const float* scbn_g = (const float*)d_in[16];
    const float* scbn_b = (const float*)d_in[17];

    char* ws = (char*)d_ws;
    float* st = (float*)(ws + WS_STATS);
    float* bn1_sum = st + 0,    *bn1_sq = st + 134;
    float* bnsc_sum = st + 268, *bnsc_sq = st + 396;
    float* bn2_sum = st + 524,  *bn2_sq = st + 658;
    float* bn3_sum = st + 792,  *bn3_sq = st + 920;
    float* a1 = st + 1048, *c1 = st + 1182;
    float* a2 = st + 1316, *c2 = st + 1450;
    float* a3 = st + 1584, *c3 = st + 1712;
    float* asc = st + 1840, *csc = st + 1968;

    unsigned short* WT1 = (unsigned short*)(ws + WS_WT1);
    unsigned short* WT2 = (unsigned short*)(ws + WS_WT2);
    unsigned short* WT3 = (unsigned short*)(ws + WS_WT3);
    float* SQN = (float*)(ws + WS_SQN);
    int*   IDX = (int*)(ws + WS_IDX);
    unsigned short* X   = (unsigned short*)(ws + WS_X);
    unsigned short* Z   = (unsigned short*)(ws + WS_Z);
    unsigned short* ZSC = (unsigned short*)(ws + WS_ZSC);
    unsigned short* H   = (unsigned short*)(ws + WS_H);
    float* out = (float*)d_out;

    hipMemsetAsync(ws + WS_STATS, 0, 1048 * 4, stream);

    fill_wt<<<54, 256, 0, stream>>>(WT1, fc1_w, 67, 144, 134, 96);
    fill_wt<<<48, 256, 0, stream>>>(WT1 + 144 * 96, sc_w, 67, 128, 128, 96);
    fill_wt<<<90, 256, 0, stream>>>(WT2, fc2_w, 134, 144, 134, 160);
    fill_wt<<<80, 256, 0, stream>>>(WT3, fc3_w, 134, 128, 128, 160);

    fps_kernel<<<8, 256, 0, stream>>>(xyz, out);
    sqn_kernel<<<128, 256, 0, stream>>>(xyz, SQN);
    knn_kernel<<<2048, 256, 0, stream>>>(xyz, SQN, out, IDX);
    build_x<<<49152, 256, 0, stream>>>(xyz, pts, out, IDX, X);

    // GEMM1 fused with shortcut GEMM: X[M,96] @ Wt[272,96]^T -> z1 (134 of 144) | zsc (128)
    gemm_bn<96, 17><<<1024, 256, 0, stream>>>(X, WT1,
        Z, 144, 134, bn1_sum, bn1_sq,
        ZSC, 128, 128, bnsc_sum, bnsc_sq, 144);
    bn_finalize<<<1, 256, 0, stream>>>(bn1_sum, bn1_sq, bn1_g, bn1_b, a1, c1, 134);
    bn_finalize<<<1, 256, 0, stream>>>(bnsc_sum, bnsc_sq, scbn_g, scbn_b, asc, csc, 128);
    norm_relu<<<81920, 256, 0, stream>>>(Z, 144, 134, H, 160, a1, c1, (size_t)M_ * 160);

    gemm_bn<160, 9><<<1024, 256, 0, stream>>>(H, WT2,
        Z, 144, 134, bn2_sum, bn2_sq,
        Z, 144, 0, bn2_sum, bn2_sq, 144);
    bn_finalize<<<1, 256, 0, stream>>>(bn2_sum, bn2_sq, bn2_g, bn2_b, a2, c2, 134);
    norm_relu<<<81920, 256, 0, stream>>>(Z, 144, 134, H, 160, a2, c2, (size_t)M_ * 160);

    gemm_bn<160, 8><<<1024, 256, 0, stream>>>(H, WT3,
        Z, 128, 128, bn3_sum, bn3_sq,
        Z, 128, 0, bn3_sum, bn3_sq, 128);
    bn_finalize<<<1, 256, 0, stream>>>(bn3_sum, bn3_sq, bn3_g, bn3_b, a3, c3, 128);

    final_kernel<<<4096, 256, 0, stream>>>(Z, ZSC, a3, c3, asc, csc, out);
}

// Round 3
// 1123.813 us; speedup vs baseline: 1.7698x; 1.0138x over previous
//
#include <hip/hip_runtime.h>
#include <cstdint>
#include <cstddef>

typedef short short8 __attribute__((ext_vector_type(8)));
typedef float f32x4 __attribute__((ext_vector_type(4)));

#define B_   8
#define N_   4096
#define S_   1024
#define K_   16
#define M_   131072   /* B*S*K */
#define CIN_ 64

__device__ inline float bf2f(unsigned short u) {
    unsigned int v = ((unsigned int)u) << 16;
    return __builtin_bit_cast(float, v);
}
__device__ inline unsigned short f2bf(float f) {
    unsigned int u = __builtin_bit_cast(unsigned int, f);
    unsigned int lsb = (u >> 16) & 1u;
    u += 0x7fffu + lsb;
    return (unsigned short)(u >> 16);
}

// ---------------- FPS helper: packed-key DPP max ----------------
template<int CTRL>
__device__ inline unsigned long long dpp_max(unsigned long long k) {
    unsigned lo = (unsigned)k, hi = (unsigned)(k >> 32);
    unsigned olo = (unsigned)__builtin_amdgcn_update_dpp(0, (int)lo, CTRL, 0xF, 0xF, true);
    unsigned ohi = (unsigned)__builtin_amdgcn_update_dpp(0, (int)hi, CTRL, 0xF, 0xF, true);
    unsigned long long ok = ((unsigned long long)ohi << 32) | (unsigned long long)olo;
    return ok > k ? ok : k;   // keys >= 0, DPP 0-fill on undefined lanes is harmless for max
}

// ---------------- FPS: one block per batch, sequential 1024 steps ----------------
// 256 threads (4 waves, 1 wave/SIMD). Points pinned in VGPRs; LDS mirror for
// centroid lookup; NO global memory ops inside the step loop. Wave reduce is
// 6 all-DPP rounds (no ds_swizzle/bpermute on the critical path); lane 63 of
// each wave holds the wave max after ROW_BCAST15+ROW_BCAST31.
__global__ __launch_bounds__(256) void fps_kernel(const float* __restrict__ xyz,
                                                  float* __restrict__ outxyz)
{
    __shared__ float px_s[N_], py_s[N_], pz_s[N_];   // 48 KB point mirror
    __shared__ float sOut[S_ * 3];                   // 12 KB output staging
    __shared__ unsigned long long sK[2][4];
    int b = blockIdx.x;
    const float* xb = xyz + (size_t)b * N_ * 3;
    int t = threadIdx.x;
    int w = t >> 6, l = t & 63;
    const int NP = 16;
    float px[NP], py[NP], pz[NP], dst[NP];
#pragma unroll
    for (int i = 0; i < NP; i++) {
        int p = i * 256 + t;
        px[i] = xb[p * 3 + 0];
        py[i] = xb[p * 3 + 1];
        pz[i] = xb[p * 3 + 2];
        dst[i] = 1e10f;
        px_s[p] = px[i]; py_s[p] = py[i]; pz_s[p] = pz[i];
        asm volatile("" : "+v"(px[i]), "+v"(py[i]), "+v"(pz[i]));  // pin in VGPRs
    }
    __syncthreads();
    float cx = px_s[0], cy = py_s[0], cz = pz_s[0];  // far = 0 deterministic start
    for (int s = 0; s < S_; s++) {
        if (t == 0) { sOut[s * 3 + 0] = cx; sOut[s * 3 + 1] = cy; sOut[s * 3 + 2] = cz; }
        if (s == S_ - 1) break;
        float bd = -1.0f; int bp = 0;
#pragma unroll
        for (int i = 0; i < NP; i++) {
            // exact ref semantics: plain mul/add, no FMA contraction
            float dx = __fsub_rn(px[i], cx);
            float dy = __fsub_rn(py[i], cy);
            float dz = __fsub_rn(pz[i], cz);
            float d  = __fadd_rn(__fadd_rn(__fmul_rn(dx, dx), __fmul_rn(dy, dy)),
                                 __fmul_rn(dz, dz));
            float nd = fminf(dst[i], d);
            dst[i] = nd;
            if (nd > bd) { bd = nd; bp = i * 256 + t; }  // strict >: lowest i on tie
        }
        // pack: d >= 0 so float bits are order-preserving; (4095-idx) => tie -> lowest idx
        unsigned long long key =
            ((unsigned long long)__builtin_bit_cast(unsigned, bd) << 32) |
            (unsigned long long)(unsigned)(4095 - bp);
        key = dpp_max<0xB1>(key);   // quad_perm [1,0,3,2] : lane ^ 1
        key = dpp_max<0x4E>(key);   // quad_perm [2,3,0,1] : lane ^ 2
        key = dpp_max<0x141>(key);  // row_half_mirror     : 8-group reduce
        key = dpp_max<0x140>(key);  // row_mirror          : 16-row reduce
        key = dpp_max<0x142>(key);  // ROW_BCAST15: rows 1,3 absorb rows 0,2
        key = dpp_max<0x143>(key);  // ROW_BCAST31: rows 2,3 absorb 0,1 -> lanes 48-63 = wave max
        int par = s & 1;
        if (l == 63) sK[par][w] = key;
        __syncthreads();
        unsigned long long k0 = sK[par][0], k1 = sK[par][1];
        unsigned long long k2 = sK[par][2], k3 = sK[par][3];
        unsigned long long ka = k0 > k1 ? k0 : k1;
        unsigned long long kb = k2 > k3 ? k2 : k3;
        unsigned long long g  = ka > kb ? ka : kb;
        int p = 4095 - (int)(g & 0xFFFu);
        cx = px_s[p]; cy = py_s[p]; cz = pz_s[p];    // LDS broadcast (same addr all lanes)
    }
    __syncthreads();
    float* ob = outxyz + (size_t)b * S_ * 3;
    for (int i = t; i < S_ * 3; i += 256) ob[i] = sOut[i];
}

// ---------------- per-point squared norm (exact ref formula) ----------------
__global__ void sqn_kernel(const float* __restrict__ xyz, float* __restrict__ sqn)
{
    int i = blockIdx.x * 256 + threadIdx.x;
    if (i >= B_ * N_) return;
    float x = xyz[i * 3 + 0], y = xyz[i * 3 + 1], z = xyz[i * 3 + 2];
    sqn[i] = __fadd_rn(__fadd_rn(__fmul_rn(x, x), __fmul_rn(y, y)), __fmul_rn(z, z));
}

// ---------------- kNN: one wave per query ----------------
__global__ __launch_bounds__(256) void knn_kernel(const float* __restrict__ xyz,
                                                  const float* __restrict__ sqn,
                                                  const float* __restrict__ newxyz,
                                                  int* __restrict__ idx)
{
    int w = threadIdx.x >> 6, l = threadIdx.x & 63;
    int q = blockIdx.x * 4 + w;          // 0..8191
    int b = q >> 10;
    const float* xb = xyz + (size_t)b * N_ * 3;
    const float* sb = sqn + (size_t)b * N_;
    float qx = newxyz[(size_t)q * 3 + 0];
    float qy = newxyz[(size_t)q * 3 + 1];
    float qz = newxyz[(size_t)q * 3 + 2];
    float sa = __fadd_rn(__fadd_rn(__fmul_rn(qx, qx), __fmul_rn(qy, qy)), __fmul_rn(qz, qz));

    float d16[16]; int i16[16];
#pragma unroll
    for (int j = 0; j < 16; j++) { d16[j] = 3.0e38f; i16[j] = -1; }
    // d16 kept descending: d16[0] = current worst, d16[15] = best
    for (int i = 0; i < N_ / 64; i++) {
        int n = i * 64 + l;
        float bx = xb[n * 3 + 0], by = xb[n * 3 + 1], bz = xb[n * 3 + 2];
        float dot = __fmaf_rn(qz, bz, __fmaf_rn(qy, by, __fmul_rn(qx, bx)));
        float d = __fsub_rn(__fadd_rn(sa, sb[n]), __fmul_rn(2.0f, dot));
        if (d < d16[0]) {   // strict: equal keeps older (lower) index, matches stable top_k
            d16[0] = d; i16[0] = n;
#pragma unroll
            for (int j = 0; j < 15; j++) {
                if (d16[j] < d16[j + 1]) {
                    float td = d16[j]; d16[j] = d16[j + 1]; d16[j + 1] = td;
                    int   ti = i16[j]; i16[j] = i16[j + 1]; i16[j + 1] = ti;
                }
            }
        }
    }
    int* iq = idx + (size_t)q * 16;
#pragma unroll
    for (int r = 0; r < 16; r++) {
        float cd = d16[15]; int cn = i16[15];
#pragma unroll
        for (int off = 1; off < 64; off <<= 1) {
            float od = __shfl_xor(cd, off);
            int   on = __shfl_xor(cn, off);
            if (od < cd || (od == cd && on < cn)) { cd = od; cn = on; }
        }
        if (l == 0) iq[r] = cn;
        if (i16[15] == cn) {   // winner pops (n unique across lanes)
#pragma unroll
            for (int j = 15; j >= 1; j--) { d16[j] = d16[j - 1]; i16[j] = i16[j - 1]; }
            d16[0] = 3.0e38f; i16[0] = -1;
        }
    }
}

// ---------------- build X = [grouped_xyz_norm | grouped_pts | 0pad] (bf16) ----------------
// 6 threads per row, 16 cols each, vectorized b128 stores.
__global__ void build_x(const float* __restrict__ xyz, const float* __restrict__ pts,
                        const float* __restrict__ newxyz, const int* __restrict__ idx,
                        unsigned short* __restrict__ X)
{
    int tid = blockIdx.x * 256 + threadIdx.x;   // M*6 = 786432 exactly
    int j = tid % 6;
    int r = tid / 6;
    float v[16];
#pragma unroll
    for (int e = 0; e < 16; e++) v[e] = 0.0f;
    if (j < 5) {
        int n = idx[r];
        int s = (r >> 4) & 1023;
        int b = r >> 14;
        const float* pr = pts + ((size_t)b * N_ + n) * CIN_;
        if (j == 0) {
#pragma unroll
            for (int c = 0; c < 3; c++)
                v[c] = xyz[((size_t)b * N_ + n) * 3 + c] - newxyz[((size_t)b * S_ + s) * 3 + c];
#pragma unroll
            for (int c = 3; c < 16; c++) v[c] = pr[c - 3];
        } else if (j == 4) {
#pragma unroll
            for (int c = 0; c < 3; c++) v[c] = pr[61 + c];
        } else {
            int base = j * 16 - 3;
#pragma unroll
            for (int c = 0; c < 16; c++) v[c] = pr[base + c];
        }
    }
    short8 lo, hi;
#pragma unroll
    for (int e = 0; e < 8; e++) { lo[e] = (short)f2bf(v[e]); hi[e] = (short)f2bf(v[8 + e]); }
    unsigned short* xp = X + (size_t)r * 96 + j * 16;
    *(short8*)xp = lo;
    *(short8*)(xp + 8) = hi;
}

// ---------------- weight prep: transpose + pad to bf16 [Nrows][KPAD] ----------------
__global__ void fill_wt(unsigned short* __restrict__ dst, const float* __restrict__ src,
                        int Kreal, int Nrows, int Nsrc, int KPAD)
{
    int tid = blockIdx.x * 256 + threadIdx.x;
    if (tid >= Nrows * KPAD) return;
    int row = tid / KPAD, k = tid % KPAD;
    float v = (k < Kreal && row < Nsrc) ? src[(size_t)k * Nsrc + row] : 0.0f;
    dst[tid] = f2bf(v);
}

// ---------------- MFMA GEMM with fused BN-stat accumulation ----------------
template<int KPAD, int NF>
__global__ __launch_bounds__(256) void gemm_bn(
    const unsigned short* __restrict__ A, const unsigned short* __restrict__ Wt,
    unsigned short* __restrict__ Z1, int ld1, int n1real, float* sum1, float* sq1,
    unsigned short* __restrict__ Z2, int ld2, int n2real, float* sum2, float* sq2,
    int split)
{
    __shared__ unsigned short sA[128 * KPAD];
    __shared__ float sSt[NF * 32];
    int t = threadIdx.x;
    int r0 = blockIdx.x * 128;
    for (int i = t; i < NF * 32; i += 256) sSt[i] = 0.0f;
    {
        const uint4* ga = (const uint4*)(A + (size_t)r0 * KPAD);
        uint4* la = (uint4*)sA;
        const int CNT = 128 * KPAD * 2 / 16;
        for (int i = t; i < CNT; i += 256) la[i] = ga[i];
    }
    __syncthreads();
    int w = t >> 6, l = t & 63, lhi = l >> 4, llo = l & 15;
    f32x4 acc[2][NF];
#pragma unroll
    for (int m = 0; m < 2; m++)
#pragma unroll
        for (int n = 0; n < NF; n++) acc[m][n] = (f32x4){0.f, 0.f, 0.f, 0.f};
#pragma unroll
    for (int ks = 0; ks < KPAD / 32; ks++) {
        short8 bfr[NF];
#pragma unroll
        for (int n = 0; n < NF; n++)
            bfr[n] = *(const short8*)(Wt + (size_t)(n * 16 + llo) * KPAD + ks * 32 + lhi * 8);
#pragma unroll
        for (int m = 0; m < 2; m++) {
            short8 afr = *(const short8*)(sA + (w * 32 + m * 16 + llo) * KPAD + ks * 32 + lhi * 8);
#pragma unroll
            for (int n = 0; n < NF; n++)
                acc[m][n] = __builtin_amdgcn_mfma_f32_16x16x32_bf16(afr, bfr[n], acc[m][n], 0, 0, 0);
        }
    }
#pragma unroll
    for (int n = 0; n < NF; n++) {
        int c = n * 16 + llo;
        float ss = 0.f, sq = 0.f;
#pragma unroll
        for (int m = 0; m < 2; m++) {
#pragma unroll
            for (int j = 0; j < 4; j++) {
                float v = acc[m][n][j];
                int row = r0 + w * 32 + m * 16 + lhi * 4 + j;
                unsigned short hv = f2bf(v);
                if (c < split) Z1[(size_t)row * ld1 + c] = hv;
                else           Z2[(size_t)row * ld2 + (c - split)] = hv;
                ss += v; sq += v * v;
            }
        }
        ss += __shfl_xor(ss, 16); ss += __shfl_xor(ss, 32);
        sq += __shfl_xor(sq, 16); sq += __shfl_xor(sq, 32);
        if (l < 16) { atomicAdd(&sSt[c * 2], ss); atomicAdd(&sSt[c * 2 + 1], sq); }
    }
    __syncthreads();
    for (int c = t; c < NF * 16; c += 256) {
        float ss = sSt[c * 2], sq = sSt[c * 2 + 1];
        if (c < split) {
            if (c < n1real) { atomicAdd(&sum1[c], ss); atomicAdd(&sq1[c], sq); }
        } else {
            int cc = c - split;
            if (cc < n2real) { atomicAdd(&sum2[cc], ss); atomicAdd(&sq2[cc], sq); }
        }
    }
}

// ---------------- BN finalize: a = g*rsqrt(var+eps), c = b - a*mean ----------------
__global__ void bn_finalize(const float* __restrict__ sum, const float* __restrict__ sq,
                            const float* __restrict__ g, const float* __restrict__ bb,
                            float* __restrict__ a, float* __restrict__ c, int n)
{
    int i = blockIdx.x * 256 + threadIdx.x;
    if (i >= n) return;
    const float inv = 1.0f / (float)M_;
    float m = sum[i] * inv;
    float var = sq[i] * inv - m * m;
    float av = g[i] * rsqrtf(var + 1e-5f);
    a[i] = av;
    c[i] = bb[i] - av * m;
}

// ---------------- normalize + relu + repad (vectorized: 8 cols/thread) ----------------
// Z: [M][144] (cols 0..133 real, 134..143 zero), H: [M][160] (134..159 forced 0)
__global__ void norm_relu_v(const unsigned short* __restrict__ Z,
                            unsigned short* __restrict__ H,
                            const float* __restrict__ a, const float* __restrict__ c)
{
    int tid = blockIdx.x * 256 + threadIdx.x;   // M*20 = 2621440 exactly
    int j = tid % 20;
    size_t r = (size_t)(tid / 20);
    int col0 = j * 8;
    short8 hv = {0, 0, 0, 0, 0, 0, 0, 0};
    if (col0 < 134) {
        short8 zv = *(const short8*)(Z + r * 144 + col0);
#pragma unroll
        for (int e = 0; e < 8; e++) {
            int col = col0 + e;
            float av = a[col], cv = c[col];           // col<136: within a|c arrays (adjacent)
            float v = fmaxf(av * bf2f((unsigned short)zv[e]) + cv, 0.0f);
            hv[e] = (col < 134) ? (short)f2bf(v) : (short)0;
        }
    }
    *(short8*)(H + r * 160 + col0) = hv;
}

// ---------------- final: bn3(z3)+bnsc(zsc), relu, max over K (8 ch/thread) ----------------
__global__ void final_kernel(const unsigned short* __restrict__ Z3,
                             const unsigned short* __restrict__ ZSC,
                             const float* __restrict__ a3, const float* __restrict__ c3,
                             const float* __restrict__ asc, const float* __restrict__ csc,
                             float* __restrict__ out)
{
    int tid = blockIdx.x * 256 + threadIdx.x;   // 8192*16 = 131072 exactly
    int bs = tid >> 4, ch0 = (tid & 15) * 8;
    float A3[8], C3[8], AS[8], CS[8], mx[8];
#pragma unroll
    for (int e = 0; e < 8; e++) {
        A3[e] = a3[ch0 + e]; C3[e] = c3[ch0 + e];
        AS[e] = asc[ch0 + e]; CS[e] = csc[ch0 + e];
        mx[e] = 0.0f;
    }
    const unsigned short* z3p = Z3 + (size_t)bs * 16 * 128 + ch0;
    const unsigned short* zsp = ZSC + (size_t)bs * 16 * 128 + ch0;
#pragma unroll
    for (int k = 0; k < 16; k++) {
        short8 z3 = *(const short8*)(z3p + (size_t)k * 128);
        short8 zs = *(const short8*)(zsp + (size_t)k * 128);
#pragma unroll
        for (int e = 0; e < 8; e++) {
            float y = fmaxf(A3[e] * bf2f((unsigned short)z3[e]) + C3[e]
                            + AS[e] * bf2f((unsigned short)zs[e]) + CS[e], 0.0f);
            mx[e] = fmaxf(mx[e], y);
        }
    }
    float* op = out + 24576 + (size_t)bs * 128 + ch0;
#pragma unroll
    for (int e = 0; e < 8; e++) op[e] = mx[e];
}

// ---------------- workspace layout (bytes) ----------------
#define WS_STATS 0
#define WS_WT1   16384
#define WS_WT2   68608
#define WS_WT3   114688
#define WS_SQN   155648
#define WS_IDX   286720
#define WS_X     811008
#define WS_Z     25976832
#define WS_ZSC   63725568
#define WS_H     97280000

extern "C" void kernel_launch(void* const* d_in, const int* in_sizes, int n_in,
                              void* d_out, int out_size, void* d_ws, size_t ws_size,
                              hipStream_t stream)
{
    const float* xyz    = (const float*)d_in[0];
    const float* pts    = (const float*)d_in[1];
    const float* fc1_w  = (const float*)d_in[2];
    const float* bn1_g  = (const float*)d_in[4];
    const float* bn1_b  = (const float*)d_in[5];
    const float* fc2_w  = (const float*)d_in[6];
    const float* bn2_g  = (const float*)d_in[8];
    const float* bn2_b  = (const float*)d_in[9];
    const float* fc3_w  = (const float*)d_in[10];
    const float* bn3_g  = (const float*)d_in[12];
    const float* bn3_b  = (const float*)d_in[13];
    const float* sc_w   = (const float*)d_in[14];
    const float* scbn_g = (const float*)d_in[16];
    const float* scbn_b = (const float*)d_in[17];

    char* ws = (char*)d_ws;
    float* st = (float*)(ws + WS_STATS);
    float* bn1_sum = st + 0,    *bn1_sq = st + 134;
    float* bnsc_sum = st + 268, *bnsc_sq = st + 396;
    float* bn2_sum = st + 524,  *bn2_sq = st + 658;
    float* bn3_sum = st + 792,  *bn3_sq = st + 920;
    float* a1 = st + 1048, *c1 = st + 1182;
    float* a2 = st + 1316, *c2 = st + 1450;
    float* a3 = st + 1584, *c3 = st + 1712;
    float* asc = st + 1840, *csc = st + 1968;

    unsigned short* WT1 = (unsigned short*)(ws + WS_WT1);
    unsigned short* WT2 = (unsigned short*)(ws + WS_WT2);
    unsigned short* WT3 = (unsigned short*)(ws + WS_WT3);
    float* SQN = (float*)(ws + WS_SQN);
    int*   IDX = (int*)(ws + WS_IDX);
    unsigned short* X   = (unsigned short*)(ws + WS_X);
    unsigned short* Z   = (unsigned short*)(ws + WS_Z);
    unsigned short* ZSC = (unsigned short*)(ws + WS_ZSC);
    unsigned short* H   = (unsigned short*)(ws + WS_H);
    float* out = (float*)d_out;

    hipMemsetAsync(ws + WS_STATS, 0, 1048 * 4, stream);

    fill_wt<<<54, 256, 0, stream>>>(WT1, fc1_w, 67, 144, 134, 96);
    fill_wt<<<48, 256, 0, stream>>>(WT1 + 144 * 96, sc_w, 67, 128, 128, 96);
    fill_wt<<<90, 256, 0, stream>>>(WT2, fc2_w, 134, 144, 134, 160);
    fill_wt<<<80, 256, 0, stream>>>(WT3, fc3_w, 134, 128, 128, 160);

    fps_kernel<<<8, 256, 0, stream>>>(xyz, out);
    sqn_kernel<<<128, 256, 0, stream>>>(xyz, SQN);
    knn_kernel<<<2048, 256, 0, stream>>>(xyz, SQN, out, IDX);
    build_x<<<3072, 256, 0, stream>>>(xyz, pts, out, IDX, X);

    // GEMM1 fused with shortcut GEMM: X[M,96] @ Wt[272,96]^T -> z1 (134 of 144) | zsc (128)
    gemm_bn<96, 17><<<1024, 256, 0, stream>>>(X, WT1,
        Z, 144, 134, bn1_sum, bn1_sq,
        ZSC, 128, 128, bnsc_sum, bnsc_sq, 144);
    bn_finalize<<<1, 256, 0, stream>>>(bn1_sum, bn1_sq, bn1_g, bn1_b, a1, c1, 134);
    bn_finalize<<<1, 256, 0, stream>>>(bnsc_sum, bnsc_sq, scbn_g, scbn_b, asc, csc, 128);
    norm_relu_v<<<10240, 256, 0, stream>>>(Z, H, a1, c1);

    gemm_bn<160, 9><<<1024, 256, 0, stream>>>(H, WT2,
        Z, 144, 134, bn2_sum, bn2_sq,
        Z, 144, 0, bn2_sum, bn2_sq, 144);
    bn_finalize<<<1, 256, 0, stream>>>(bn2_sum, bn2_sq, bn2_g, bn2_b, a2, c2, 134);
    norm_relu_v<<<10240, 256, 0, stream>>>(Z, H, a2, c2);

    gemm_bn<160, 8><<<1024, 256, 0, stream>>>(H, WT3,
        Z, 128, 128, bn3_sum, bn3_sq,
        Z, 128, 0, bn3_sum, bn3_sq, 128);
    bn_finalize<<<1, 256, 0, stream>>>(bn3_sum, bn3_sq, bn3_g, bn3_b, a3, c3, 128);

    final_kernel<<<512, 256, 0, stream>>>(Z, ZSC, a3, c3, asc, csc, out);
}

// Round 4
// 1037.134 us; speedup vs baseline: 1.9177x; 1.0836x over previous
//
#include <hip/hip_runtime.h>
#include <cstdint>
#include <cstddef>

typedef short short8 __attribute__((ext_vector_type(8)));
typedef float f32x4 __attribute__((ext_vector_type(4)));
typedef unsigned long long u64x2 __attribute__((ext_vector_type(2)));

#define B_   8
#define N_   4096
#define S_   1024
#define K_   16
#define M_   131072   /* B*S*K */
#define CIN_ 64

__device__ inline float bf2f(unsigned short u) {
    unsigned int v = ((unsigned int)u) << 16;
    return __builtin_bit_cast(float, v);
}
__device__ inline unsigned short f2bf(float f) {
    unsigned int u = __builtin_bit_cast(unsigned int, f);
    unsigned int lsb = (u >> 16) & 1u;
    u += 0x7fffu + lsb;
    return (unsigned short)(u >> 16);
}

// ---------------- FPS helper: packed-key DPP max ----------------
template<int CTRL>
__device__ inline unsigned long long dpp_max(unsigned long long k) {
    unsigned lo = (unsigned)k, hi = (unsigned)(k >> 32);
    unsigned olo = (unsigned)__builtin_amdgcn_update_dpp(0, (int)lo, CTRL, 0xF, 0xF, true);
    unsigned ohi = (unsigned)__builtin_amdgcn_update_dpp(0, (int)hi, CTRL, 0xF, 0xF, true);
    unsigned long long ok = ((unsigned long long)ohi << 32) | (unsigned long long)olo;
    return ok > k ? ok : k;   // keys >= 0, DPP 0-fill on undefined lanes harmless for max
}

// ---------------- FPS (blocks 0-7) + concurrent aux prep (blocks 8-47) ----------------
// FPS: 256 threads, points pinned in VGPRs, LDS mirror for centroid lookup,
// no global ops in the serial loop, 6-round all-DPP wave reduce, one barrier/step.
// Aux blocks: weight transpose/pad (WT1|WT1sc|WT2|WT3) + per-point sq-norms,
// riding on idle CUs while FPS runs (removes 5 dispatches from critical path).
__global__ __launch_bounds__(256) void fps_aux_kernel(
    const float* __restrict__ xyz, float* __restrict__ outxyz,
    const float* __restrict__ fc1_w, const float* __restrict__ sc_w,
    const float* __restrict__ fc2_w, const float* __restrict__ fc3_w,
    unsigned short* __restrict__ WT1, unsigned short* __restrict__ WT2,
    unsigned short* __restrict__ WT3, float* __restrict__ sqn)
{
    __shared__ float px_s[N_], py_s[N_], pz_s[N_];   // 48 KB point mirror
    __shared__ float sOut[S_ * 3];                   // 12 KB output staging
    __shared__ unsigned long long sK[2][4];
    int t = threadIdx.x;

    if (blockIdx.x >= 8) {
        int aux = blockIdx.x - 8;   // 0..39, each covers 10*256 flat elems
#pragma unroll
        for (int ch = 0; ch < 10; ch++) {
            int idx = (aux * 10 + ch) * 256 + t;    // 0..102399
            if (idx < 13824) {                      // WT1 (fc1): [144][96]
                int row = idx / 96, k = idx % 96;
                WT1[idx] = f2bf((k < 67 && row < 134) ? fc1_w[k * 134 + row] : 0.0f);
            } else if (idx < 26112) {               // WT1sc: [128][96]
                int j = idx - 13824;
                int row = j / 96, k = j % 96;
                WT1[13824 + j] = f2bf((k < 67) ? sc_w[k * 128 + row] : 0.0f);
            } else if (idx < 49152) {               // WT2: [144][160]
                int j = idx - 26112;
                int row = j / 160, k = j % 160;
                WT2[j] = f2bf((k < 134 && row < 134) ? fc2_w[k * 134 + row] : 0.0f);
            } else if (idx < 69632) {               // WT3: [128][160]
                int j = idx - 49152;
                int row = j / 160, k = j % 160;
                WT3[j] = f2bf((k < 134) ? fc3_w[k * 128 + row] : 0.0f);
            } else {                                // sqn: 32768 points
                int i = idx - 69632;
                float x = xyz[i * 3 + 0], y = xyz[i * 3 + 1], z = xyz[i * 3 + 2];
                sqn[i] = __fadd_rn(__fadd_rn(__fmul_rn(x, x), __fmul_rn(y, y)),
                                   __fmul_rn(z, z));
            }
        }
        return;
    }

    int b = blockIdx.x;
    const float* xb = xyz + (size_t)b * N_ * 3;
    int w = t >> 6, l = t & 63;
    const int NP = 16;
    float px[NP], py[NP], pz[NP], dst[NP];
    int klo_[NP];
#pragma unroll
    for (int i = 0; i < NP; i++) {
        int p = i * 256 + t;
        px[i] = xb[p * 3 + 0];
        py[i] = xb[p * 3 + 1];
        pz[i] = xb[p * 3 + 2];
        dst[i] = 1e10f;
        klo_[i] = 4095 - p;                          // pre-baked tie-break key
        px_s[p] = px[i]; py_s[p] = py[i]; pz_s[p] = pz[i];
        asm volatile("" : "+v"(px[i]), "+v"(py[i]), "+v"(pz[i]));  // pin in VGPRs
    }
    __syncthreads();
    float cx = px_s[0], cy = py_s[0], cz = pz_s[0];  // far = 0 deterministic start
    for (int s = 0; s < S_; s++) {
        if (t == 0) { sOut[s * 3 + 0] = cx; sOut[s * 3 + 1] = cy; sOut[s * 3 + 2] = cz; }
        if (s == S_ - 1) break;
        float bd = -1.0f; int bk = 0;
#pragma unroll
        for (int i = 0; i < NP; i++) {
            // exact ref semantics: plain mul/add, no FMA contraction
            float dx = __fsub_rn(px[i], cx);
            float dy = __fsub_rn(py[i], cy);
            float dz = __fsub_rn(pz[i], cz);
            float d  = __fadd_rn(__fadd_rn(__fmul_rn(dx, dx), __fmul_rn(dy, dy)),
                                 __fmul_rn(dz, dz));
            float nd = fminf(dst[i], d);
            dst[i] = nd;
            if (nd > bd) { bd = nd; bk = klo_[i]; }  // strict >: lowest idx on tie
        }
        // d >= 0 so float bits are order-preserving; (4095-idx) => tie -> lowest idx
        unsigned long long key =
            ((unsigned long long)__builtin_bit_cast(unsigned, bd) << 32) |
            (unsigned long long)(unsigned)bk;
        key = dpp_max<0xB1>(key);   // lane ^ 1
        key = dpp_max<0x4E>(key);   // lane ^ 2
        key = dpp_max<0x141>(key);  // row_half_mirror (8-group)
        key = dpp_max<0x140>(key);  // row_mirror (16-group)
        key = dpp_max<0x142>(key);  // row_bcast15 -> 32
        key = dpp_max<0x143>(key);  // row_bcast31 -> 64; lanes 48-63 hold wave max
        int par = s & 1;
        if (l == 63) sK[par][w] = key;
        __syncthreads();
        u64x2 kA = *(u64x2*)&sK[par][0];
        u64x2 kB = *(u64x2*)&sK[par][2];
        unsigned long long ka = kA[0] > kA[1] ? kA[0] : kA[1];
        unsigned long long kb = kB[0] > kB[1] ? kB[0] : kB[1];
        unsigned long long g  = ka > kb ? ka : kb;
        int p = 4095 - (int)(g & 0xFFFu);
        cx = px_s[p]; cy = py_s[p]; cz = pz_s[p];    // LDS broadcast
    }
    __syncthreads();
    float* ob = outxyz + (size_t)b * S_ * 3;
    for (int i = t; i < S_ * 3; i += 256) ob[i] = sOut[i];
}

// ---------------- kNN (one wave per query) + fused X build ----------------
__global__ __launch_bounds__(256) void knn_build(const float* __restrict__ xyz,
                                                 const float* __restrict__ sqn,
                                                 const float* __restrict__ newxyz,
                                                 const float* __restrict__ pts,
                                                 unsigned short* __restrict__ X)
{
    __shared__ int sNbr[4][16];
    int w = threadIdx.x >> 6, l = threadIdx.x & 63;
    int q = blockIdx.x * 4 + w;          // 0..8191
    int b = q >> 10;
    const float* xb = xyz + (size_t)b * N_ * 3;
    const float* sb = sqn + (size_t)b * N_;
    float qx = newxyz[(size_t)q * 3 + 0];
    float qy = newxyz[(size_t)q * 3 + 1];
    float qz = newxyz[(size_t)q * 3 + 2];
    float sa = __fadd_rn(__fadd_rn(__fmul_rn(qx, qx), __fmul_rn(qy, qy)), __fmul_rn(qz, qz));

    float d16[16]; int i16[16];
#pragma unroll
    for (int j = 0; j < 16; j++) { d16[j] = 3.0e38f; i16[j] = -1; }
    // d16 kept descending: d16[0] = current worst, d16[15] = best
    for (int i = 0; i < N_ / 64; i++) {
        int n = i * 64 + l;
        float bx = xb[n * 3 + 0], by = xb[n * 3 + 1], bz = xb[n * 3 + 2];
        float dot = __fmaf_rn(qz, bz, __fmaf_rn(qy, by, __fmul_rn(qx, bx)));
        float d = __fsub_rn(__fadd_rn(sa, sb[n]), __fmul_rn(2.0f, dot));
        if (d < d16[0]) {   // strict: equal keeps older (lower) index, matches stable top_k
            d16[0] = d; i16[0] = n;
#pragma unroll
            for (int j = 0; j < 15; j++) {
                if (d16[j] < d16[j + 1]) {
                    float td = d16[j]; d16[j] = d16[j + 1]; d16[j + 1] = td;
                    int   ti = i16[j]; i16[j] = i16[j + 1]; i16[j + 1] = ti;
                }
            }
        }
    }
#pragma unroll
    for (int r = 0; r < 16; r++) {
        float cd = d16[15]; int cn = i16[15];
#pragma unroll
        for (int off = 1; off < 64; off <<= 1) {
            float od = __shfl_xor(cd, off);
            int   on = __shfl_xor(cn, off);
            if (od < cd || (od == cd && on < cn)) { cd = od; cn = on; }
        }
        if (l == 0) sNbr[w][r] = cn;
        if (i16[15] == cn) {   // winner pops (n unique across lanes)
#pragma unroll
            for (int j = 15; j >= 1; j--) { d16[j] = d16[j - 1]; i16[j] = i16[j - 1]; }
            d16[0] = 3.0e38f; i16[0] = -1;
        }
    }
    __syncthreads();
    // build X rows q*16..q*16+15: 4 lanes per row, 24 cols each
    int row = l >> 2, seg = l & 3;
    int n = sNbr[w][row];
    const float* pr = pts + ((size_t)b * N_ + n) * CIN_;
    const float* xr = xyz + ((size_t)b * N_ + n) * 3;
    float v[24];
#pragma unroll
    for (int e = 0; e < 24; e++) {
        int c = seg * 24 + e;
        float val;
        if (c == 0)      val = xr[0] - qx;
        else if (c == 1) val = xr[1] - qy;
        else if (c == 2) val = xr[2] - qz;
        else if (c < 67) val = pr[c - 3];
        else             val = 0.0f;
        v[e] = val;
    }
    short8 s0, s1, s2;
#pragma unroll
    for (int e = 0; e < 8; e++) {
        s0[e] = (short)f2bf(v[e]);
        s1[e] = (short)f2bf(v[8 + e]);
        s2[e] = (short)f2bf(v[16 + e]);
    }
    unsigned short* xp = X + ((size_t)q * 16 + row) * 96 + seg * 24;
    *(short8*)xp = s0;
    *(short8*)(xp + 8) = s1;
    *(short8*)(xp + 16) = s2;
}

// ---------------- MFMA GEMM with fused BN-stat accumulation ----------------
template<int KPAD, int NF>
__global__ __launch_bounds__(256) void gemm_bn(
    const unsigned short* __restrict__ A, const unsigned short* __restrict__ Wt,
    unsigned short* __restrict__ Z1, int ld1, int n1real, float* sum1, float* sq1)
{
    __shared__ unsigned short sA[128 * KPAD];
    __shared__ float sSt[NF * 32];
    int t = threadIdx.x;
    int r0 = blockIdx.x * 128;
    for (int i = t; i < NF * 32; i += 256) sSt[i] = 0.0f;
    {
        const uint4* ga = (const uint4*)(A + (size_t)r0 * KPAD);
        uint4* la = (uint4*)sA;
        const int CNT = 128 * KPAD * 2 / 16;
        for (int i = t; i < CNT; i += 256) la[i] = ga[i];
    }
    __syncthreads();
    int w = t >> 6, l = t & 63, lhi = l >> 4, llo = l & 15;
    f32x4 acc[2][NF];
#pragma unroll
    for (int m = 0; m < 2; m++)
#pragma unroll
        for (int n = 0; n < NF; n++) acc[m][n] = (f32x4){0.f, 0.f, 0.f, 0.f};
#pragma unroll
    for (int ks = 0; ks < KPAD / 32; ks++) {
        short8 bfr[NF];
#pragma unroll
        for (int n = 0; n < NF; n++)
            bfr[n] = *(const short8*)(Wt + (size_t)(n * 16 + llo) * KPAD + ks * 32 + lhi * 8);
#pragma unroll
        for (int m = 0; m < 2; m++) {
            short8 afr = *(const short8*)(sA + (w * 32 + m * 16 + llo) * KPAD + ks * 32 + lhi * 8);
#pragma unroll
            for (int n = 0; n < NF; n++)
                acc[m][n] = __builtin_amdgcn_mfma_f32_16x16x32_bf16(afr, bfr[n], acc[m][n], 0, 0, 0);
        }
    }
#pragma unroll
    for (int n = 0; n < NF; n++) {
        int c = n * 16 + llo;
        float ss = 0.f, sq = 0.f;
#pragma unroll
        for (int m = 0; m < 2; m++) {
#pragma unroll
            for (int j = 0; j < 4; j++) {
                float v = acc[m][n][j];
                int row = r0 + w * 32 + m * 16 + lhi * 4 + j;
                Z1[(size_t)row * ld1 + c] = f2bf(v);
                ss += v; sq += v * v;
            }
        }
        ss += __shfl_xor(ss, 16); ss += __shfl_xor(ss, 32);
        sq += __shfl_xor(sq, 16); sq += __shfl_xor(sq, 32);
        if (l < 16) { atomicAdd(&sSt[c * 2], ss); atomicAdd(&sSt[c * 2 + 1], sq); }
    }
    __syncthreads();
    for (int c = t; c < NF * 16; c += 256) {
        if (c < n1real) {
            atomicAdd(&sum1[c], sSt[c * 2]);
            atomicAdd(&sq1[c], sSt[c * 2 + 1]);
        }
    }
}

// ---------------- normalize + relu + repad, BN finalize fused (LDS) ----------------
// Z: [M][144] (cols 0..133 real), H: [M][160] (134..159 forced 0)
__global__ __launch_bounds__(256) void norm_relu_v(const unsigned short* __restrict__ Z,
                                                   unsigned short* __restrict__ H,
                                                   const float* __restrict__ sum,
                                                   const float* __restrict__ sq,
                                                   const float* __restrict__ g,
                                                   const float* __restrict__ bb)
{
    __shared__ float sAC[272];   // interleaved {a,c} for 136 cols
    int t = threadIdx.x;
    if (t < 136) {
        float a = 0.0f, c = 0.0f;
        if (t < 134) {
            const float inv = 1.0f / (float)M_;
            float m = sum[t] * inv;
            float var = sq[t] * inv - m * m;
            a = g[t] * rsqrtf(var + 1e-5f);
            c = bb[t] - a * m;
        }
        sAC[2 * t] = a; sAC[2 * t + 1] = c;
    }
    __syncthreads();
    int tid = blockIdx.x * 256 + t;   // M*20 = 2621440 exactly
    int j = tid % 20;
    size_t r = (size_t)(tid / 20);
    int col0 = j * 8;
    short8 hv = {0, 0, 0, 0, 0, 0, 0, 0};
    if (col0 < 134) {
        short8 zv = *(const short8*)(Z + r * 144 + col0);
#pragma unroll
        for (int e = 0; e < 8; e++) {
            int col = col0 + e;
            float2 ac = *(float2*)&sAC[2 * col];
            float v = fmaxf(ac.x * bf2f((unsigned short)zv[e]) + ac.y, 0.0f);
            hv[e] = (col < 134) ? (short)f2bf(v) : (short)0;
        }
    }
    *(short8*)(H + r * 160 + col0) = hv;
}

// ---------------- final: bn3+bnsc (finalize fused), relu, max over K ----------------
__global__ __launch_bounds__(256) void final_kernel(
    const unsigned short* __restrict__ Z3, const unsigned short* __restrict__ ZSC,
    const float* __restrict__ sum3, const float* __restrict__ sq3,
    const float* __restrict__ g3, const float* __restrict__ b3,
    const float* __restrict__ sumsc, const float* __restrict__ sqsc,
    const float* __restrict__ gsc, const float* __restrict__ bsc,
    float* __restrict__ out)
{
    __shared__ float sF[512];   // per-ch {a3,c3,asc,csc}
    int t = threadIdx.x;
    if (t < 128) {
        const float inv = 1.0f / (float)M_;
        float m3 = sum3[t] * inv, v3 = sq3[t] * inv - m3 * m3;
        float a3 = g3[t] * rsqrtf(v3 + 1e-5f), c3 = b3[t] - a3 * m3;
        float ms = sumsc[t] * inv, vs = sqsc[t] * inv - ms * ms;
        float as = gsc[t] * rsqrtf(vs + 1e-5f), cs = bsc[t] - as * ms;
        sF[t * 4 + 0] = a3; sF[t * 4 + 1] = c3; sF[t * 4 + 2] = as; sF[t * 4 + 3] = cs;
    }
    __syncthreads();
    int tid = blockIdx.x * 256 + t;   // 8192*16 = 131072 exactly
    int bs = tid >> 4, ch0 = (tid & 15) * 8;
    float A3[8], C3[8], AS[8], CS[8], mx[8];
#pragma unroll
    for (int e = 0; e < 8; e++) {
        f32x4 f = *(f32x4*)&sF[(ch0 + e) * 4];
        A3[e] = f[0]; C3[e] = f[1]; AS[e] = f[2]; CS[e] = f[3];
        mx[e] = 0.0f;
    }
    const unsigned short* z3p = Z3 + (size_t)bs * 16 * 128 + ch0;
    const unsigned short* zsp = ZSC + (size_t)bs * 16 * 128 + ch0;
#pragma unroll
    for (int k = 0; k < 16; k++) {
        short8 z3 = *(const short8*)(z3p + (size_t)k * 128);
        short8 zs = *(const short8*)(zsp + (size_t)k * 128);
#pragma unroll
        for (int e = 0; e < 8; e++) {
            float y = fmaxf(A3[e] * bf2f((unsigned short)z3[e]) + C3[e]
                            + AS[e] * bf2f((unsigned short)zs[e]) + CS[e], 0.0f);
            mx[e] = fmaxf(mx[e], y);
        }
    }
    float* op = out + 24576 + (size_t)bs * 128 + ch0;
#pragma unroll
    for (int e = 0; e < 8; e++) op[e] = mx[e];
}

// ---------------- workspace layout (bytes) ----------------
#define WS_STATS 0           /* 1056 floats (sum/sq x4, padded strides) */
#define WS_WT1   8192        /* 26112 bf16 */
#define WS_WT2   61440       /* 23040 bf16 */
#define WS_WT3   108544      /* 20480 bf16 */
#define WS_SQN   149760      /* 32768 f32 */
#define WS_X     281088      /* M*96 bf16 */
#define WS_Z     25447424    /* M*144 bf16 */
#define WS_ZSC   63196416    /* M*128 bf16 */
#define WS_H     96751104    /* M*160 bf16; end ~138.7 MB */

extern "C" void kernel_launch(void* const* d_in, const int* in_sizes, int n_in,
                              void* d_out, int out_size, void* d_ws, size_t ws_size,
                              hipStream_t stream)
{
    const float* xyz    = (const float*)d_in[0];
    const float* pts    = (const float*)d_in[1];
    const float* fc1_w  = (const float*)d_in[2];
    const float* bn1_g  = (const float*)d_in[4];
    const float* bn1_b  = (const float*)d_in[5];
    const float* fc2_w  = (const float*)d_in[6];
    const float* bn2_g  = (const float*)d_in[8];
    const float* bn2_b  = (const float*)d_in[9];
    const float* fc3_w  = (const float*)d_in[10];
    const float* bn3_g  = (const float*)d_in[12];
    const float* bn3_b  = (const float*)d_in[13];
    const float* sc_w   = (const float*)d_in[14];
    const float* scbn_g = (const float*)d_in[16];
    const float* scbn_b = (const float*)d_in[17];

    char* ws = (char*)d_ws;
    float* st = (float*)(ws + WS_STATS);
    float* bn1_sum = st + 0,   *bn1_sq = st + 136;
    float* bnsc_sum = st + 272, *bnsc_sq = st + 400;
    float* bn2_sum = st + 528, *bn2_sq = st + 664;
    float* bn3_sum = st + 800, *bn3_sq = st + 928;

    unsigned short* WT1 = (unsigned short*)(ws + WS_WT1);
    unsigned short* WT2 = (unsigned short*)(ws + WS_WT2);
    unsigned short* WT3 = (unsigned short*)(ws + WS_WT3);
    float* SQN = (float*)(ws + WS_SQN);
    unsigned short* X   = (unsigned short*)(ws + WS_X);
    unsigned short* Z   = (unsigned short*)(ws + WS_Z);
    unsigned short* ZSC = (unsigned short*)(ws + WS_ZSC);
    unsigned short* H   = (unsigned short*)(ws + WS_H);
    float* out = (float*)d_out;

    hipMemsetAsync(ws + WS_STATS, 0, 1056 * 4, stream);

    fps_aux_kernel<<<48, 256, 0, stream>>>(xyz, out, fc1_w, sc_w, fc2_w, fc3_w,
                                           WT1, WT2, WT3, SQN);
    knn_build<<<2048, 256, 0, stream>>>(xyz, SQN, out, pts, X);

    gemm_bn<96, 9><<<1024, 256, 0, stream>>>(X, WT1, Z, 144, 134, bn1_sum, bn1_sq);
    gemm_bn<96, 8><<<1024, 256, 0, stream>>>(X, WT1 + 13824, ZSC, 128, 128, bnsc_sum, bnsc_sq);
    norm_relu_v<<<10240, 256, 0, stream>>>(Z, H, bn1_sum, bn1_sq, bn1_g, bn1_b);

    gemm_bn<160, 9><<<1024, 256, 0, stream>>>(H, WT2, Z, 144, 134, bn2_sum, bn2_sq);
    norm_relu_v<<<10240, 256, 0, stream>>>(Z, H, bn2_sum, bn2_sq, bn2_g, bn2_b);

    gemm_bn<160, 8><<<1024, 256, 0, stream>>>(H, WT3, Z, 128, 128, bn3_sum, bn3_sq);

    final_kernel<<<512, 256, 0, stream>>>(Z, ZSC, bn3_sum, bn3_sq, bn3_g, bn3_b,
                                          bnsc_sum, bnsc_sq, scbn_g, scbn_b, out);
}

// Round 5
// 972.578 us; speedup vs baseline: 2.0450x; 1.0664x over previous
//
#include <hip/hip_runtime.h>
#include <cstdint>
#include <cstddef>

typedef short short8 __attribute__((ext_vector_type(8)));
typedef float f32x4 __attribute__((ext_vector_type(4)));
typedef unsigned long long u64x2 __attribute__((ext_vector_type(2)));

#define B_   8
#define N_   4096
#define S_   1024
#define K_   16
#define M_   131072   /* B*S*K */
#define CIN_ 64

__device__ inline float bf2f(unsigned short u) {
    unsigned int v = ((unsigned int)u) << 16;
    return __builtin_bit_cast(float, v);
}
__device__ inline unsigned short f2bf(float f) {
    unsigned int u = __builtin_bit_cast(unsigned int, f);
    unsigned int lsb = (u >> 16) & 1u;
    u += 0x7fffu + lsb;
    return (unsigned short)(u >> 16);
}

// ---------------- FPS helper: packed-key DPP max ----------------
template<int CTRL>
__device__ inline unsigned long long dpp_max(unsigned long long k) {
    unsigned lo = (unsigned)k, hi = (unsigned)(k >> 32);
    unsigned olo = (unsigned)__builtin_amdgcn_update_dpp(0, (int)lo, CTRL, 0xF, 0xF, true);
    unsigned ohi = (unsigned)__builtin_amdgcn_update_dpp(0, (int)hi, CTRL, 0xF, 0xF, true);
    unsigned long long ok = ((unsigned long long)ohi << 32) | (unsigned long long)olo;
    return ok > k ? ok : k;   // keys >= 0, DPP 0-fill on undefined lanes harmless for max
}

// ---------------- FPS (blocks 0-7) + concurrent aux prep (blocks 8-47) ----------------
__global__ __launch_bounds__(256) void fps_aux_kernel(
    const float* __restrict__ xyz, float* __restrict__ outxyz,
    const float* __restrict__ fc1_w, const float* __restrict__ sc_w,
    const float* __restrict__ fc2_w, const float* __restrict__ fc3_w,
    unsigned short* __restrict__ WT1, unsigned short* __restrict__ WT2,
    unsigned short* __restrict__ WT3, float* __restrict__ sqn)
{
    __shared__ float px_s[N_], py_s[N_], pz_s[N_];   // 48 KB point mirror
    __shared__ float sOut[S_ * 3];                   // 12 KB output staging
    __shared__ __attribute__((aligned(16))) unsigned long long sK[2][4];
    int t = threadIdx.x;

    if (blockIdx.x >= 8) {
        int aux = blockIdx.x - 8;   // 0..39, each covers 10*256 flat elems
#pragma unroll
        for (int ch = 0; ch < 10; ch++) {
            int idx = (aux * 10 + ch) * 256 + t;    // 0..102399
            if (idx < 13824) {                      // WT1 (fc1): [144][96]
                int row = idx / 96, k = idx % 96;
                WT1[idx] = f2bf((k < 67 && row < 134) ? fc1_w[k * 134 + row] : 0.0f);
            } else if (idx < 26112) {               // WT1sc: [128][96]
                int j = idx - 13824;
                int row = j / 96, k = j % 96;
                WT1[13824 + j] = f2bf((k < 67) ? sc_w[k * 128 + row] : 0.0f);
            } else if (idx < 49152) {               // WT2: [144][160]
                int j = idx - 26112;
                int row = j / 160, k = j % 160;
                WT2[j] = f2bf((k < 134 && row < 134) ? fc2_w[k * 134 + row] : 0.0f);
            } else if (idx < 69632) {               // WT3: [128][160]
                int j = idx - 49152;
                int row = j / 160, k = j % 160;
                WT3[j] = f2bf((k < 134) ? fc3_w[k * 128 + row] : 0.0f);
            } else {                                // sqn: 32768 points
                int i = idx - 69632;
                float x = xyz[i * 3 + 0], y = xyz[i * 3 + 1], z = xyz[i * 3 + 2];
                sqn[i] = __fadd_rn(__fadd_rn(__fmul_rn(x, x), __fmul_rn(y, y)),
                                   __fmul_rn(z, z));
            }
        }
        return;
    }

    int b = blockIdx.x;
    const float* xb = xyz + (size_t)b * N_ * 3;
    int w = t >> 6, l = t & 63;
    const int NP = 16;
    float px[NP], py[NP], pz[NP], dst[NP];
#pragma unroll
    for (int i = 0; i < NP; i++) {
        int p = i * 256 + t;
        px[i] = xb[p * 3 + 0];
        py[i] = xb[p * 3 + 1];
        pz[i] = xb[p * 3 + 2];
        dst[i] = 1e10f;
        px_s[p] = px[i]; py_s[p] = py[i]; pz_s[p] = pz[i];
        asm volatile("" : "+v"(px[i]), "+v"(py[i]), "+v"(pz[i]));  // pin in VGPRs
    }
    __syncthreads();
    float cx = px_s[0], cy = py_s[0], cz = pz_s[0];  // far = 0 deterministic start
    for (int s = 0; s < S_; s++) {
        if (t == 0) { sOut[s * 3 + 0] = cx; sOut[s * 3 + 1] = cy; sOut[s * 3 + 2] = cz; }
        if (s == S_ - 1) break;
        float bd = -1.0f; int bp = 0;
#pragma unroll
        for (int i = 0; i < NP; i++) {
            // exact ref semantics: plain mul/add, no FMA contraction
            float dx = __fsub_rn(px[i], cx);
            float dy = __fsub_rn(py[i], cy);
            float dz = __fsub_rn(pz[i], cz);
            float d  = __fadd_rn(__fadd_rn(__fmul_rn(dx, dx), __fmul_rn(dy, dy)),
                                 __fmul_rn(dz, dz));
            float nd = fminf(dst[i], d);
            dst[i] = nd;
            if (nd > bd) { bd = nd; bp = i * 256 + t; }  // strict >: lowest idx on tie
        }
        // d >= 0 so float bits are order-preserving; (4095-idx) => tie -> lowest idx
        unsigned long long key =
            ((unsigned long long)__builtin_bit_cast(unsigned, bd) << 32) |
            (unsigned long long)(unsigned)(4095 - bp);
        key = dpp_max<0xB1>(key);   // lane ^ 1
        key = dpp_max<0x4E>(key);   // lane ^ 2
        key = dpp_max<0x141>(key);  // row_half_mirror (8-group)
        key = dpp_max<0x140>(key);  // row_mirror (16-group)
        key = dpp_max<0x142>(key);  // row_bcast15 -> 32
        key = dpp_max<0x143>(key);  // row_bcast31 -> 64; lanes 48-63 hold wave max
        int par = s & 1;
        if (l == 63) sK[par][w] = key;
        __syncthreads();
        u64x2 kA = *(u64x2*)&sK[par][0];
        u64x2 kB = *(u64x2*)&sK[par][2];
        unsigned long long ka = kA[0] > kA[1] ? kA[0] : kA[1];
        unsigned long long kb = kB[0] > kB[1] ? kB[0] : kB[1];
        unsigned long long g  = ka > kb ? ka : kb;
        int p = 4095 - (int)(g & 0xFFFu);
        cx = px_s[p]; cy = py_s[p]; cz = pz_s[p];    // LDS broadcast
    }
    __syncthreads();
    float* ob = outxyz + (size_t)b * S_ * 3;
    for (int i = t; i < S_ * 3; i += 256) ob[i] = sOut[i];
}

// ---------------- kNN (one wave per query) + fused X build ----------------
__global__ __launch_bounds__(256) void knn_build(const float* __restrict__ xyz,
                                                 const float* __restrict__ sqn,
                                                 const float* __restrict__ newxyz,
                                                 const float* __restrict__ pts,
                                                 unsigned short* __restrict__ X)
{
    __shared__ int sNbr[4][16];
    int w = threadIdx.x >> 6, l = threadIdx.x & 63;
    int q = blockIdx.x * 4 + w;          // 0..8191
    int b = q >> 10;
    const float* xb = xyz + (size_t)b * N_ * 3;
    const float* sb = sqn + (size_t)b * N_;
    float qx = newxyz[(size_t)q * 3 + 0];
    float qy = newxyz[(size_t)q * 3 + 1];
    float qz = newxyz[(size_t)q * 3 + 2];
    float sa = __fadd_rn(__fadd_rn(__fmul_rn(qx, qx), __fmul_rn(qy, qy)), __fmul_rn(qz, qz));

    float d16[16]; int i16[16];
#pragma unroll
    for (int j = 0; j < 16; j++) { d16[j] = 3.0e38f; i16[j] = -1; }
    // d16 kept descending: d16[0] = current worst, d16[15] = best
    for (int i = 0; i < N_ / 64; i++) {
        int n = i * 64 + l;
        float bx = xb[n * 3 + 0], by = xb[n * 3 + 1], bz = xb[n * 3 + 2];
        float dot = __fmaf_rn(qz, bz, __fmaf_rn(qy, by, __fmul_rn(qx, bx)));
        float d = __fsub_rn(__fadd_rn(sa, sb[n]), __fmul_rn(2.0f, dot));
        if (d < d16[0]) {   // strict: equal keeps older (lower) index, matches stable top_k
            d16[0] = d; i16[0] = n;
#pragma unroll
            for (int j = 0; j < 15; j++) {
                if (d16[j] < d16[j + 1]) {
                    float td = d16[j]; d16[j] = d16[j + 1]; d16[j + 1] = td;
                    int   ti = i16[j]; i16[j] = i16[j + 1]; i16[j + 1] = ti;
                }
            }
        }
    }
#pragma unroll
    for (int r = 0; r < 16; r++) {
        float cd = d16[15]; int cn = i16[15];
#pragma unroll
        for (int off = 1; off < 64; off <<= 1) {
            float od = __shfl_xor(cd, off);
            int   on = __shfl_xor(cn, off);
            if (od < cd || (od == cd && on < cn)) { cd = od; cn = on; }
        }
        if (l == 0) sNbr[w][r] = cn;
        if (i16[15] == cn) {   // winner pops (n unique across lanes)
#pragma unroll
            for (int j = 15; j >= 1; j--) { d16[j] = d16[j - 1]; i16[j] = i16[j - 1]; }
            d16[0] = 3.0e38f; i16[0] = -1;
        }
    }
    __syncthreads();
    // build X rows q*16..q*16+15: 4 lanes per row, 24 cols each
    int row = l >> 2, seg = l & 3;
    int n = sNbr[w][row];
    const float* pr = pts + ((size_t)b * N_ + n) * CIN_;
    const float* xr = xyz + ((size_t)b * N_ + n) * 3;
    float v[24];
#pragma unroll
    for (int e = 0; e < 24; e++) {
        int c = seg * 24 + e;
        float val;
        if (c == 0)      val = xr[0] - qx;
        else if (c == 1) val = xr[1] - qy;
        else if (c == 2) val = xr[2] - qz;
        else if (c < 67) val = pr[c - 3];
        else             val = 0.0f;
        v[e] = val;
    }
    short8 s0, s1, s2;
#pragma unroll
    for (int e = 0; e < 8; e++) {
        s0[e] = (short)f2bf(v[e]);
        s1[e] = (short)f2bf(v[8 + e]);
        s2[e] = (short)f2bf(v[16 + e]);
    }
    unsigned short* xp = X + ((size_t)q * 16 + row) * 96 + seg * 24;
    *(short8*)xp = s0;
    *(short8*)(xp + 8) = s1;
    *(short8*)(xp + 16) = s2;
}

// ---------------- MFMA GEMM core: fused BN-stats, optional BN+ReLU staging,
//                  conflict-padded LDS, coalesced epilogue via LDS transpose ----
template<int KPAD, int NF, bool BNST>
__device__ __forceinline__ void gemm_core(
    const unsigned short* __restrict__ A, const unsigned short* __restrict__ Wt,
    unsigned short* __restrict__ Zo, float* __restrict__ sum, float* __restrict__ sq,
    int nreal, const float* __restrict__ ps, const float* __restrict__ pq,
    const float* __restrict__ pg, const float* __restrict__ pb,
    int r0, unsigned short* sBuf, float* sSt, float* sAC, int t)
{
    constexpr int AST = KPAD + 8;        // padded stride: 2-way-max bank aliasing
    for (int i = t; i < NF * 32; i += 256) sSt[i] = 0.0f;
    if (BNST) {
        // per-block BN finalize from global sums (deterministic, identical per block)
        if (t < 160) {
            float a = 0.f, c = 0.f;
            if (t < 134) {
                const float inv = 1.0f / (float)M_;
                float m = ps[t] * inv;
                float var = pq[t] * inv - m * m;
                a = pg[t] * rsqrtf(var + 1e-5f);
                c = pb[t] - a * m;
            }
            sAC[2 * t] = a; sAC[2 * t + 1] = c;
        }
        __syncthreads();
        // stage: relu(a*z+c) from Zin[M][144] -> sBuf[128][AST] (cols>=134 -> 0)
#pragma unroll
        for (int c8 = 0; c8 < 10; c8++) {
            int chunk = c8 * 256 + t;                  // 2560 = 128 rows * 20 chunks
            int row = chunk / 20, col0 = (chunk % 20) * 8;
            short8 hv = {0, 0, 0, 0, 0, 0, 0, 0};
            if (col0 < 144) {
                short8 zv = *(const short8*)(A + (size_t)(r0 + row) * 144 + col0);
#pragma unroll
                for (int e = 0; e < 8; e++) {
                    float2 ac = *(float2*)&sAC[2 * (col0 + e)];
                    float v = fmaxf(ac.x * bf2f((unsigned short)zv[e]) + ac.y, 0.0f);
                    hv[e] = (short)f2bf(v);
                }
            }
            *(short8*)(sBuf + row * AST + col0) = hv;
        }
    } else {
#pragma unroll
        for (int c8 = 0; c8 < (128 * KPAD / 8) / 256; c8++) {
            int chunk = c8 * 256 + t;
            int row = chunk / (KPAD / 8), col0 = (chunk % (KPAD / 8)) * 8;
            *(short8*)(sBuf + row * AST + col0) =
                *(const short8*)(A + (size_t)(r0 + row) * KPAD + col0);
        }
    }
    __syncthreads();
    int w = t >> 6, l = t & 63, lhi = l >> 4, llo = l & 15;
    f32x4 acc[2][NF];
#pragma unroll
    for (int m = 0; m < 2; m++)
#pragma unroll
        for (int n = 0; n < NF; n++) acc[m][n] = (f32x4){0.f, 0.f, 0.f, 0.f};
#pragma unroll
    for (int ks = 0; ks < KPAD / 32; ks++) {
        short8 bfr[NF];
#pragma unroll
        for (int n = 0; n < NF; n++)
            bfr[n] = *(const short8*)(Wt + (size_t)(n * 16 + llo) * KPAD + ks * 32 + lhi * 8);
#pragma unroll
        for (int m = 0; m < 2; m++) {
            short8 afr = *(const short8*)(sBuf + (w * 32 + m * 16 + llo) * AST + ks * 32 + lhi * 8);
#pragma unroll
            for (int n = 0; n < NF; n++)
                acc[m][n] = __builtin_amdgcn_mfma_f32_16x16x32_bf16(afr, bfr[n], acc[m][n], 0, 0, 0);
        }
    }
    __syncthreads();   // all waves done reading A-tile; reuse sBuf as output tile
    constexpr int OST = NF * 16 + 8;
#pragma unroll
    for (int n = 0; n < NF; n++) {
        int c = n * 16 + llo;
        float ss = 0.f, sqv = 0.f;
#pragma unroll
        for (int m = 0; m < 2; m++) {
#pragma unroll
            for (int j = 0; j < 4; j++) {
                float v = acc[m][n][j];
                int row = w * 32 + m * 16 + lhi * 4 + j;
                sBuf[row * OST + c] = f2bf(v);
                ss += v; sqv += v * v;
            }
        }
        ss += __shfl_xor(ss, 16); ss += __shfl_xor(ss, 32);
        sqv += __shfl_xor(sqv, 16); sqv += __shfl_xor(sqv, 32);
        if (l < 16) { atomicAdd(&sSt[c * 2], ss); atomicAdd(&sSt[c * 2 + 1], sqv); }
    }
    __syncthreads();
    // coalesced row-major store of the 128 x NF*16 tile
#pragma unroll
    for (int c8 = 0; c8 < NF; c8++) {
        int chunk = c8 * 256 + t;                  // 128 * NF*2 chunks
        int row = chunk / (NF * 2), cc = chunk % (NF * 2);
        *(short8*)(Zo + (size_t)(r0 + row) * (NF * 16) + cc * 8) =
            *(const short8*)(sBuf + row * OST + cc * 8);
    }
    for (int c = t; c < NF * 16; c += 256) {
        if (c < nreal) {
            atomicAdd(&sum[c], sSt[c * 2]);
            atomicAdd(&sq[c], sSt[c * 2 + 1]);
        }
    }
}

// gemm1 + shortcut gemm fused in one dispatch (both read X)
__global__ __launch_bounds__(256) void gemm1_fused(
    const unsigned short* __restrict__ X, const unsigned short* __restrict__ WT1,
    unsigned short* __restrict__ Z1, unsigned short* __restrict__ ZSC,
    float* s1, float* q1, float* ssc, float* qsc)
{
    __shared__ unsigned short sBuf[21504];
    __shared__ float sSt[288];
    int t = threadIdx.x;
    if (blockIdx.x < 1024)
        gemm_core<96, 9, false>(X, WT1, Z1, s1, q1, 134,
                                nullptr, nullptr, nullptr, nullptr,
                                blockIdx.x * 128, sBuf, sSt, nullptr, t);
    else
        gemm_core<96, 8, false>(X, WT1 + 13824, ZSC, ssc, qsc, 128,
                                nullptr, nullptr, nullptr, nullptr,
                                (blockIdx.x - 1024) * 128, sBuf, sSt, nullptr, t);
}

// layer2: stages relu(bn1(Z1)) inline
__global__ __launch_bounds__(256) void gemm_l2(
    const unsigned short* __restrict__ Zin, const unsigned short* __restrict__ WT,
    unsigned short* __restrict__ Zout, float* sum, float* sq,
    const float* ps, const float* pq, const float* pg, const float* pb)
{
    __shared__ unsigned short sBuf[21504];
    __shared__ float sSt[288];
    __shared__ float sAC[320];
    gemm_core<160, 9, true>(Zin, WT, Zout, sum, sq, 134, ps, pq, pg, pb,
                            blockIdx.x * 128, sBuf, sSt, sAC, threadIdx.x);
}

// layer3: stages relu(bn2(Z2)) inline
__global__ __launch_bounds__(256) void gemm_l3(
    const unsigned short* __restrict__ Zin, const unsigned short* __restrict__ WT,
    unsigned short* __restrict__ Zout, float* sum, float* sq,
    const float* ps, const float* pq, const float* pg, const float* pb)
{
    __shared__ unsigned short sBuf[21504];
    __shared__ float sSt[288];
    __shared__ float sAC[320];
    gemm_core<160, 8, true>(Zin, WT, Zout, sum, sq, 128, ps, pq, pg, pb,
                            blockIdx.x * 128, sBuf, sSt, sAC, threadIdx.x);
}

// ---------------- final: bn3+bnsc (finalize fused), relu, max over K ----------------
__global__ __launch_bounds__(256) void final_kernel(
    const unsigned short* __restrict__ Z3, const unsigned short* __restrict__ ZSC,
    const float* __restrict__ sum3, const float* __restrict__ sq3,
    const float* __restrict__ g3, const float* __restrict__ b3,
    const float* __restrict__ sumsc, const float* __restrict__ sqsc,
    const float* __restrict__ gsc, const float* __restrict__ bsc,
    float* __restrict__ out)
{
    __shared__ float sF[512];   // per-ch {a3,c3,asc,csc}
    int t = threadIdx.x;
    if (t < 128) {
        const float inv = 1.0f / (float)M_;
        float m3 = sum3[t] * inv, v3 = sq3[t] * inv - m3 * m3;
        float a3 = g3[t] * rsqrtf(v3 + 1e-5f), c3 = b3[t] - a3 * m3;
        float ms = sumsc[t] * inv, vs = sqsc[t] * inv - ms * ms;
        float as = gsc[t] * rsqrtf(vs + 1e-5f), cs = bsc[t] - as * ms;
        sF[t * 4 + 0] = a3; sF[t * 4 + 1] = c3; sF[t * 4 + 2] = as; sF[t * 4 + 3] = cs;
    }
    __syncthreads();
    int tid = blockIdx.x * 256 + t;   // 8192*16 = 131072 exactly
    int bs = tid >> 4, ch0 = (tid & 15) * 8;
    float A3[8], C3[8], AS[8], CS[8], mx[8];
#pragma unroll
    for (int e = 0; e < 8; e++) {
        f32x4 f = *(f32x4*)&sF[(ch0 + e) * 4];
        A3[e] = f[0]; C3[e] = f[1]; AS[e] = f[2]; CS[e] = f[3];
        mx[e] = 0.0f;
    }
    const unsigned short* z3p = Z3 + (size_t)bs * 16 * 128 + ch0;
    const unsigned short* zsp = ZSC + (size_t)bs * 16 * 128 + ch0;
#pragma unroll
    for (int k = 0; k < 16; k++) {
        short8 z3 = *(const short8*)(z3p + (size_t)k * 128);
        short8 zs = *(const short8*)(zsp + (size_t)k * 128);
#pragma unroll
        for (int e = 0; e < 8; e++) {
            float y = fmaxf(A3[e] * bf2f((unsigned short)z3[e]) + C3[e]
                            + AS[e] * bf2f((unsigned short)zs[e]) + CS[e], 0.0f);
            mx[e] = fmaxf(mx[e], y);
        }
    }
    float* op = out + 24576 + (size_t)bs * 128 + ch0;
#pragma unroll
    for (int e = 0; e < 8; e++) op[e] = mx[e];
}

// ---------------- workspace layout (bytes) ----------------
#define WS_STATS 0           /* 1056 floats */
#define WS_WT1   8192        /* 26112 bf16 */
#define WS_WT2   61440       /* 23040 bf16 */
#define WS_WT3   108544      /* 20480 bf16 */
#define WS_SQN   149760      /* 32768 f32 */
#define WS_X     281088      /* M*96 bf16 */
#define WS_Z1    25447424    /* M*144 bf16 (reused as Z3 [M][128]) */
#define WS_ZSC   63196416    /* M*128 bf16 */
#define WS_Z2    96751104    /* M*144 bf16; end ~134.5 MB */

extern "C" void kernel_launch(void* const* d_in, const int* in_sizes, int n_in,
                              void* d_out, int out_size, void* d_ws, size_t ws_size,
                              hipStream_t stream)
{
    const float* xyz    = (const float*)d_in[0];
    const float* pts    = (const float*)d_in[1];
    const float* fc1_w  = (const float*)d_in[2];
    const float* bn1_g  = (const float*)d_in[4];
    const float* bn1_b  = (const float*)d_in[5];
    const float* fc2_w  = (const float*)d_in[6];
    const float* bn2_g  = (const float*)d_in[8];
    const float* bn2_b  = (const float*)d_in[9];
    const float* fc3_w  = (const float*)d_in[10];
    const float* bn3_g  = (const float*)d_in[12];
    const float* bn3_b  = (const float*)d_in[13];
    const float* sc_w   = (const float*)d_in[14];
    const float* scbn_g = (const float*)d_in[16];
    const float* scbn_b = (const float*)d_in[17];

    char* ws = (char*)d_ws;
    float* st = (float*)(ws + WS_STATS);
    float* bn1_sum = st + 0,    *bn1_sq = st + 136;
    float* bnsc_sum = st + 272, *bnsc_sq = st + 400;
    float* bn2_sum = st + 528,  *bn2_sq = st + 664;
    float* bn3_sum = st + 800,  *bn3_sq = st + 928;

    unsigned short* WT1 = (unsigned short*)(ws + WS_WT1);
    unsigned short* WT2 = (unsigned short*)(ws + WS_WT2);
    unsigned short* WT3 = (unsigned short*)(ws + WS_WT3);
    float* SQN = (float*)(ws + WS_SQN);
    unsigned short* X   = (unsigned short*)(ws + WS_X);
    unsigned short* Z1  = (unsigned short*)(ws + WS_Z1);
    unsigned short* ZSC = (unsigned short*)(ws + WS_ZSC);
    unsigned short* Z2  = (unsigned short*)(ws + WS_Z2);
    unsigned short* Z3  = Z1;   // Z1 dead after gemm_l2
    float* out = (float*)d_out;

    hipMemsetAsync(ws + WS_STATS, 0, 1056 * 4, stream);

    fps_aux_kernel<<<48, 256, 0, stream>>>(xyz, out, fc1_w, sc_w, fc2_w, fc3_w,
                                           WT1, WT2, WT3, SQN);
    knn_build<<<2048, 256, 0, stream>>>(xyz, SQN, out, pts, X);

    gemm1_fused<<<2048, 256, 0, stream>>>(X, WT1, Z1, ZSC,
                                          bn1_sum, bn1_sq, bnsc_sum, bnsc_sq);
    gemm_l2<<<1024, 256, 0, stream>>>(Z1, WT2, Z2, bn2_sum, bn2_sq,
                                      bn1_sum, bn1_sq, bn1_g, bn1_b);
    gemm_l3<<<1024, 256, 0, stream>>>(Z2, WT3, Z3, bn3_sum, bn3_sq,
                                      bn2_sum, bn2_sq, bn2_g, bn2_b);

    final_kernel<<<512, 256, 0, stream>>>(Z3, ZSC, bn3_sum, bn3_sq, bn3_g, bn3_b,
                                          bnsc_sum, bnsc_sq, scbn_g, scbn_b, out);
}

// Round 6
// 957.999 us; speedup vs baseline: 2.0761x; 1.0152x over previous
//
#include <hip/hip_runtime.h>
#include <cstdint>
#include <cstddef>

typedef short short8 __attribute__((ext_vector_type(8)));
typedef float f32x4 __attribute__((ext_vector_type(4)));
typedef unsigned long long u64x2 __attribute__((ext_vector_type(2)));

#define B_   8
#define N_   4096
#define S_   1024
#define K_   16
#define M_   131072   /* B*S*K */
#define CIN_ 64

__device__ inline float bf2f(unsigned short u) {
    unsigned int v = ((unsigned int)u) << 16;
    return __builtin_bit_cast(float, v);
}
__device__ inline unsigned short f2bf(float f) {
    unsigned int u = __builtin_bit_cast(unsigned int, f);
    unsigned int lsb = (u >> 16) & 1u;
    u += 0x7fffu + lsb;
    return (unsigned short)(u >> 16);
}

// ---------------- FPS helper: f32 DPP max round ----------------
template<int CTRL>
__device__ inline float dpp_maxf(float x) {
    int xi = __builtin_bit_cast(int, x);
    int yi = __builtin_amdgcn_update_dpp(0, xi, CTRL, 0xF, 0xF, true);  // 0-fill ok: bd >= 0
    return fmaxf(x, __builtin_bit_cast(float, yi));
}

// ---------------- FPS (blocks 0-7) + concurrent aux prep (blocks 8-47) ----------------
// t-major point ownership (p = t*16+i): lane order == point order, so the
// wave argmax is f32-only DPP max + ballot + ctz + readlane — exact
// lowest-index tie-break with no u64 compares on the critical path.
__global__ __launch_bounds__(256) void fps_aux_kernel(
    const float* __restrict__ xyz, float* __restrict__ outxyz,
    const float* __restrict__ fc1_w, const float* __restrict__ sc_w,
    const float* __restrict__ fc2_w, const float* __restrict__ fc3_w,
    unsigned short* __restrict__ WT1, unsigned short* __restrict__ WT2,
    unsigned short* __restrict__ WT3, float* __restrict__ sqn)
{
    __shared__ float px_s[N_], py_s[N_], pz_s[N_];   // 48 KB point mirror
    __shared__ float sOut[S_ * 3];                   // 12 KB output staging
    __shared__ __attribute__((aligned(16))) unsigned long long sK[2][4];
    int t = threadIdx.x;

    if (blockIdx.x >= 8) {
        int aux = blockIdx.x - 8;   // 0..39, each covers 10*256 flat elems
#pragma unroll
        for (int ch = 0; ch < 10; ch++) {
            int idx = (aux * 10 + ch) * 256 + t;    // 0..102399
            if (idx < 13824) {                      // WT1 (fc1): [144][96]
                int row = idx / 96, k = idx % 96;
                WT1[idx] = f2bf((k < 67 && row < 134) ? fc1_w[k * 134 + row] : 0.0f);
            } else if (idx < 26112) {               // WT1sc: [128][96]
                int j = idx - 13824;
                int row = j / 96, k = j % 96;
                WT1[13824 + j] = f2bf((k < 67) ? sc_w[k * 128 + row] : 0.0f);
            } else if (idx < 49152) {               // WT2: [144][160]
                int j = idx - 26112;
                int row = j / 160, k = j % 160;
                WT2[j] = f2bf((k < 134 && row < 134) ? fc2_w[k * 134 + row] : 0.0f);
            } else if (idx < 69632) {               // WT3: [128][160]
                int j = idx - 49152;
                int row = j / 160, k = j % 160;
                WT3[j] = f2bf((k < 134) ? fc3_w[k * 128 + row] : 0.0f);
            } else {                                // sqn: 32768 points
                int i = idx - 69632;
                float x = xyz[i * 3 + 0], y = xyz[i * 3 + 1], z = xyz[i * 3 + 2];
                sqn[i] = __fadd_rn(__fadd_rn(__fmul_rn(x, x), __fmul_rn(y, y)),
                                   __fmul_rn(z, z));
            }
        }
        return;
    }

    int b = blockIdx.x;
    const float* xb = xyz + (size_t)b * N_ * 3;
    int w = t >> 6, l = t & 63;
    const int NP = 16;
    float px[NP], py[NP], pz[NP], dst[NP];
    {
        // t-major load: thread t owns points t*16 .. t*16+15 (48 contiguous floats)
        float flat[48];
        const float4* xb4 = (const float4*)xb + t * 12;
#pragma unroll
        for (int j = 0; j < 12; j++) {
            float4 v = xb4[j];
            flat[j * 4 + 0] = v.x; flat[j * 4 + 1] = v.y;
            flat[j * 4 + 2] = v.z; flat[j * 4 + 3] = v.w;
        }
#pragma unroll
        for (int i = 0; i < NP; i++) {
            int p = t * 16 + i;
            px[i] = flat[i * 3 + 0];
            py[i] = flat[i * 3 + 1];
            pz[i] = flat[i * 3 + 2];
            dst[i] = 1e10f;
            px_s[p] = px[i]; py_s[p] = py[i]; pz_s[p] = pz[i];
            asm volatile("" : "+v"(px[i]), "+v"(py[i]), "+v"(pz[i]));  // pin in VGPRs
        }
    }
    __syncthreads();
    float cx = px_s[0], cy = py_s[0], cz = pz_s[0];  // far = 0 deterministic start
    for (int s = 0; s < S_; s++) {
        if (t == 0) { sOut[s * 3 + 0] = cx; sOut[s * 3 + 1] = cy; sOut[s * 3 + 2] = cz; }
        if (s == S_ - 1) break;
        float bd = -1.0f; int bi = 0;
#pragma unroll
        for (int i = 0; i < NP; i++) {
            // exact ref semantics: plain mul/add, no FMA contraction
            float dx = __fsub_rn(px[i], cx);
            float dy = __fsub_rn(py[i], cy);
            float dz = __fsub_rn(pz[i], cz);
            float d  = __fadd_rn(__fadd_rn(__fmul_rn(dx, dx), __fmul_rn(dy, dy)),
                                 __fmul_rn(dz, dz));
            float nd = fminf(dst[i], d);
            dst[i] = nd;
            if (nd > bd) bi = i;       // strict >: tie keeps lower i (= lower p)
            bd = fmaxf(bd, nd);
        }
        // wave max via f32-only DPP chain (lane 63 holds wave max)
        float m = bd;
        m = dpp_maxf<0xB1>(m);    // lane ^ 1
        m = dpp_maxf<0x4E>(m);    // lane ^ 2
        m = dpp_maxf<0x141>(m);   // row_half_mirror (8-group)
        m = dpp_maxf<0x140>(m);   // row_mirror (16-group)
        m = dpp_maxf<0x142>(m);   // row_bcast15 -> 32-group partial
        m = dpp_maxf<0x143>(m);   // row_bcast31 -> lane 63 = wave max
        float bw = __builtin_bit_cast(float,
                       __builtin_amdgcn_readlane(__builtin_bit_cast(int, m), 63));
        unsigned long long msk = __ballot(bd == bw);
        int wl  = (int)__builtin_ctzll(msk);                 // lowest lane = lowest p (t-major)
        int wbi = __builtin_amdgcn_readlane(bi, wl);
        int pw  = (w * 64 + wl) * 16 + wbi;                  // winner point of this wave
        unsigned long long key =
            ((unsigned long long)__builtin_bit_cast(unsigned, bw) << 32) |
            (unsigned long long)(unsigned)(4095 - pw);       // tie -> lowest p
        int par = s & 1;
        if (l == 0) sK[par][w] = key;
        __syncthreads();
        u64x2 kA = *(u64x2*)&sK[par][0];
        u64x2 kB = *(u64x2*)&sK[par][2];
        unsigned long long ka = kA[0] > kA[1] ? kA[0] : kA[1];
        unsigned long long kb = kB[0] > kB[1] ? kB[0] : kB[1];
        unsigned long long g  = ka > kb ? ka : kb;
        int p = 4095 - (int)(g & 0xFFFu);
        cx = px_s[p]; cy = py_s[p]; cz = pz_s[p];    // LDS broadcast
    }
    __syncthreads();
    float* ob = outxyz + (size_t)b * S_ * 3;
    for (int i = t; i < S_ * 3; i += 256) ob[i] = sOut[i];
}

// ---------------- kNN (one wave per query) + fused X build ----------------
__global__ __launch_bounds__(256) void knn_build(const float* __restrict__ xyz,
                                                 const float* __restrict__ sqn,
                                                 const float* __restrict__ newxyz,
                                                 const float* __restrict__ pts,
                                                 unsigned short* __restrict__ X)
{
    __shared__ int sNbr[4][16];
    int w = threadIdx.x >> 6, l = threadIdx.x & 63;
    int q = blockIdx.x * 4 + w;          // 0..8191
    int b = q >> 10;
    const float* xb = xyz + (size_t)b * N_ * 3;
    const float* sb = sqn + (size_t)b * N_;
    float qx = newxyz[(size_t)q * 3 + 0];
    float qy = newxyz[(size_t)q * 3 + 1];
    float qz = newxyz[(size_t)q * 3 + 2];
    float sa = __fadd_rn(__fadd_rn(__fmul_rn(qx, qx), __fmul_rn(qy, qy)), __fmul_rn(qz, qz));

    float d16[16]; int i16[16];
#pragma unroll
    for (int j = 0; j < 16; j++) { d16[j] = 3.0e38f; i16[j] = -1; }
    // d16 kept descending: d16[0] = current worst, d16[15] = best
    for (int i = 0; i < N_ / 64; i++) {
        int n = i * 64 + l;
        float bx = xb[n * 3 + 0], by = xb[n * 3 + 1], bz = xb[n * 3 + 2];
        float dot = __fmaf_rn(qz, bz, __fmaf_rn(qy, by, __fmul_rn(qx, bx)));
        float d = __fsub_rn(__fadd_rn(sa, sb[n]), __fmul_rn(2.0f, dot));
        if (d < d16[0]) {   // strict: equal keeps older (lower) index, matches stable top_k
            d16[0] = d; i16[0] = n;
#pragma unroll
            for (int j = 0; j < 15; j++) {
                if (d16[j] < d16[j + 1]) {
                    float td = d16[j]; d16[j] = d16[j + 1]; d16[j + 1] = td;
                    int   ti = i16[j]; i16[j] = i16[j + 1]; i16[j + 1] = ti;
                }
            }
        }
    }
#pragma unroll
    for (int r = 0; r < 16; r++) {
        float cd = d16[15]; int cn = i16[15];
#pragma unroll
        for (int off = 1; off < 64; off <<= 1) {
            float od = __shfl_xor(cd, off);
            int   on = __shfl_xor(cn, off);
            if (od < cd || (od == cd && on < cn)) { cd = od; cn = on; }
        }
        if (l == 0) sNbr[w][r] = cn;
        if (i16[15] == cn) {   // winner pops (n unique across lanes)
#pragma unroll
            for (int j = 15; j >= 1; j--) { d16[j] = d16[j - 1]; i16[j] = i16[j - 1]; }
            d16[0] = 3.0e38f; i16[0] = -1;
        }
    }
    __syncthreads();
    // build X rows q*16..q*16+15: 4 lanes per row, 24 cols each
    int row = l >> 2, seg = l & 3;
    int n = sNbr[w][row];
    const float* pr = pts + ((size_t)b * N_ + n) * CIN_;
    const float* xr = xyz + ((size_t)b * N_ + n) * 3;
    float v[24];
#pragma unroll
    for (int e = 0; e < 24; e++) {
        int c = seg * 24 + e;
        float val;
        if (c == 0)      val = xr[0] - qx;
        else if (c == 1) val = xr[1] - qy;
        else if (c == 2) val = xr[2] - qz;
        else if (c < 67) val = pr[c - 3];
        else             val = 0.0f;
        v[e] = val;
    }
    short8 s0, s1, s2;
#pragma unroll
    for (int e = 0; e < 8; e++) {
        s0[e] = (short)f2bf(v[e]);
        s1[e] = (short)f2bf(v[8 + e]);
        s2[e] = (short)f2bf(v[16 + e]);
    }
    unsigned short* xp = X + ((size_t)q * 16 + row) * 96 + seg * 24;
    *(short8*)xp = s0;
    *(short8*)(xp + 8) = s1;
    *(short8*)(xp + 16) = s2;
}

// ---------------- MFMA GEMM core: fused BN-stats, optional BN+ReLU staging,
//                  conflict-padded LDS, coalesced epilogue via LDS transpose ----
template<int KPAD, int NF, bool BNST>
__device__ __forceinline__ void gemm_core(
    const unsigned short* __restrict__ A, const unsigned short* __restrict__ Wt,
    unsigned short* __restrict__ Zo, float* __restrict__ sum, float* __restrict__ sq,
    int nreal, const float* __restrict__ ps, const float* __restrict__ pq,
    const float* __restrict__ pg, const float* __restrict__ pb,
    int r0, unsigned short* sBuf, float* sSt, float* sAC, int t)
{
    constexpr int AST = KPAD + 8;        // padded stride: 2-way-max bank aliasing
    for (int i = t; i < NF * 32; i += 256) sSt[i] = 0.0f;
    if (BNST) {
        // per-block BN finalize from global sums (deterministic, identical per block)
        if (t < 160) {
            float a = 0.f, c = 0.f;
            if (t < 134) {
                const float inv = 1.0f / (float)M_;
                float m = ps[t] * inv;
                float var = pq[t] * inv - m * m;
                a = pg[t] * rsqrtf(var + 1e-5f);
                c = pb[t] - a * m;
            }
            sAC[2 * t] = a; sAC[2 * t + 1] = c;
        }
        __syncthreads();
        // stage: relu(a*z+c) from Zin[M][144] -> sBuf[128][AST] (cols>=134 -> 0)
#pragma unroll
        for (int c8 = 0; c8 < 10; c8++) {
            int chunk = c8 * 256 + t;                  // 2560 = 128 rows * 20 chunks
            int row = chunk / 20, col0 = (chunk % 20) * 8;
            short8 hv = {0, 0, 0, 0, 0, 0, 0, 0};
            if (col0 < 144) {
                short8 zv = *(const short8*)(A + (size_t)(r0 + row) * 144 + col0);
#pragma unroll
                for (int e = 0; e < 8; e++) {
                    float2 ac = *(float2*)&sAC[2 * (col0 + e)];
                    float v = fmaxf(ac.x * bf2f((unsigned short)zv[e]) + ac.y, 0.0f);
                    hv[e] = (short)f2bf(v);
                }
            }
            *(short8*)(sBuf + row * AST + col0) = hv;
        }
    } else {
#pragma unroll
        for (int c8 = 0; c8 < (128 * KPAD / 8) / 256; c8++) {
            int chunk = c8 * 256 + t;
            int row = chunk / (KPAD / 8), col0 = (chunk % (KPAD / 8)) * 8;
            *(short8*)(sBuf + row * AST + col0) =
                *(const short8*)(A + (size_t)(r0 + row) * KPAD + col0);
        }
    }
    __syncthreads();
    int w = t >> 6, l = t & 63, lhi = l >> 4, llo = l & 15;
    f32x4 acc[2][NF];
#pragma unroll
    for (int m = 0; m < 2; m++)
#pragma unroll
        for (int n = 0; n < NF; n++) acc[m][n] = (f32x4){0.f, 0.f, 0.f, 0.f};
#pragma unroll
    for (int ks = 0; ks < KPAD / 32; ks++) {
        short8 bfr[NF];
#pragma unroll
        for (int n = 0; n < NF; n++)
            bfr[n] = *(const short8*)(Wt + (size_t)(n * 16 + llo) * KPAD + ks * 32 + lhi * 8);
#pragma unroll
        for (int m = 0; m < 2; m++) {
            short8 afr = *(const short8*)(sBuf + (w * 32 + m * 16 + llo) * AST + ks * 32 + lhi * 8);
#pragma unroll
            for (int n = 0; n < NF; n++)
                acc[m][n] = __builtin_amdgcn_mfma_f32_16x16x32_bf16(afr, bfr[n], acc[m][n], 0, 0, 0);
        }
    }
    __syncthreads();   // all waves done reading A-tile; reuse sBuf as output tile
    constexpr int OST = NF * 16 + 8;
#pragma unroll
    for (int n = 0; n < NF; n++) {
        int c = n * 16 + llo;
        float ss = 0.f, sqv = 0.f;
#pragma unroll
        for (int m = 0; m < 2; m++) {
#pragma unroll
            for (int j = 0; j < 4; j++) {
                float v = acc[m][n][j];
                int row = w * 32 + m * 16 + lhi * 4 + j;
                sBuf[row * OST + c] = f2bf(v);
                ss += v; sqv += v * v;
            }
        }
        ss += __shfl_xor(ss, 16); ss += __shfl_xor(ss, 32);
        sqv += __shfl_xor(sqv, 16); sqv += __shfl_xor(sqv, 32);
        if (l < 16) { atomicAdd(&sSt[c * 2], ss); atomicAdd(&sSt[c * 2 + 1], sqv); }
    }
    __syncthreads();
    // coalesced row-major store of the 128 x NF*16 tile
#pragma unroll
    for (int c8 = 0; c8 < NF; c8++) {
        int chunk = c8 * 256 + t;                  // 128 * NF*2 chunks
        int row = chunk / (NF * 2), cc = chunk % (NF * 2);
        *(short8*)(Zo + (size_t)(r0 + row) * (NF * 16) + cc * 8) =
            *(const short8*)(sBuf + row * OST + cc * 8);
    }
    for (int c = t; c < NF * 16; c += 256) {
        if (c < nreal) {
            atomicAdd(&sum[c], sSt[c * 2]);
            atomicAdd(&sq[c], sSt[c * 2 + 1]);
        }
    }
}

// gemm1 + shortcut gemm fused in one dispatch (both read X)
__global__ __launch_bounds__(256) void gemm1_fused(
    const unsigned short* __restrict__ X, const unsigned short* __restrict__ WT1,
    unsigned short* __restrict__ Z1, unsigned short* __restrict__ ZSC,
    float* s1, float* q1, float* ssc, float* qsc)
{
    __shared__ unsigned short sBuf[21504];
    __shared__ float sSt[288];
    int t = threadIdx.x;
    if (blockIdx.x < 1024)
        gemm_core<96, 9, false>(X, WT1, Z1, s1, q1, 134,
                                nullptr, nullptr, nullptr, nullptr,
                                blockIdx.x * 128, sBuf, sSt, nullptr, t);
    else
        gemm_core<96, 8, false>(X, WT1 + 13824, ZSC, ssc, qsc, 128,
                                nullptr, nullptr, nullptr, nullptr,
                                (blockIdx.x - 1024) * 128, sBuf, sSt, nullptr, t);
}

// layer2: stages relu(bn1(Z1)) inline
__global__ __launch_bounds__(256) void gemm_l2(
    const unsigned short* __restrict__ Zin, const unsigned short* __restrict__ WT,
    unsigned short* __restrict__ Zout, float* sum, float* sq,
    const float* ps, const float* pq, const float* pg, const float* pb)
{
    __shared__ unsigned short sBuf[21504];
    __shared__ float sSt[288];
    __shared__ float sAC[320];
    gemm_core<160, 9, true>(Zin, WT, Zout, sum, sq, 134, ps, pq, pg, pb,
                            blockIdx.x * 128, sBuf, sSt, sAC, threadIdx.x);
}

// layer3: stages relu(bn2(Z2)) inline
__global__ __launch_bounds__(256) void gemm_l3(
    const unsigned short* __restrict__ Zin, const unsigned short* __restrict__ WT,
    unsigned short* __restrict__ Zout, float* sum, float* sq,
    const float* ps, const float* pq, const float* pg, const float* pb)
{
    __shared__ unsigned short sBuf[21504];
    __shared__ float sSt[288];
    __shared__ float sAC[320];
    gemm_core<160, 8, true>(Zin, WT, Zout, sum, sq, 128, ps, pq, pg, pb,
                            blockIdx.x * 128, sBuf, sSt, sAC, threadIdx.x);
}

// ---------------- final: bn3+bnsc (finalize fused), relu, max over K ----------------
__global__ __launch_bounds__(256) void final_kernel(
    const unsigned short* __restrict__ Z3, const unsigned short* __restrict__ ZSC,
    const float* __restrict__ sum3, const float* __restrict__ sq3,
    const float* __restrict__ g3, const float* __restrict__ b3,
    const float* __restrict__ sumsc, const float* __restrict__ sqsc,
    const float* __restrict__ gsc, const float* __restrict__ bsc,
    float* __restrict__ out)
{
    __shared__ float sF[512];   // per-ch {a3,c3,asc,csc}
    int t = threadIdx.x;
    if (t < 128) {
        const float inv = 1.0f / (float)M_;
        float m3 = sum3[t] * inv, v3 = sq3[t] * inv - m3 * m3;
        float a3 = g3[t] * rsqrtf(v3 + 1e-5f), c3 = b3[t] - a3 * m3;
        float ms = sumsc[t] * inv, vs = sqsc[t] * inv - ms * ms;
        float as = gsc[t] * rsqrtf(vs + 1e-5f), cs = bsc[t] - as * ms;
        sF[t * 4 + 0] = a3; sF[t * 4 + 1] = c3; sF[t * 4 + 2] = as; sF[t * 4 + 3] = cs;
    }
    __syncthreads();
    int tid = blockIdx.x * 256 + t;   // 8192*16 = 131072 exactly
    int bs = tid >> 4, ch0 = (tid & 15) * 8;
    float A3[8], C3[8], AS[8], CS[8], mx[8];
#pragma unroll
    for (int e = 0; e < 8; e++) {
        f32x4 f = *(f32x4*)&sF[(ch0 + e) * 4];
        A3[e] = f[0]; C3[e] = f[1]; AS[e] = f[2]; CS[e] = f[3];
        mx[e] = 0.0f;
    }
    const unsigned short* z3p = Z3 + (size_t)bs * 16 * 128 + ch0;
    const unsigned short* zsp = ZSC + (size_t)bs * 16 * 128 + ch0;
#pragma unroll
    for (int k = 0; k < 16; k++) {
        short8 z3 = *(const short8*)(z3p + (size_t)k * 128);
        short8 zs = *(const short8*)(zsp + (size_t)k * 128);
#pragma unroll
        for (int e = 0; e < 8; e++) {
            float y = fmaxf(A3[e] * bf2f((unsigned short)z3[e]) + C3[e]
                            + AS[e] * bf2f((unsigned short)zs[e]) + CS[e], 0.0f);
            mx[e] = fmaxf(mx[e], y);
        }
    }
    float* op = out + 24576 + (size_t)bs * 128 + ch0;
#pragma unroll
    for (int e = 0; e < 8; e++) op[e] = mx[e];
}

// ---------------- workspace layout (bytes) ----------------
#define WS_STATS 0           /* 1056 floats */
#define WS_WT1   8192        /* 26112 bf16 */
#define WS_WT2   61440       /* 23040 bf16 */
#define WS_WT3   108544      /* 20480 bf16 */
#define WS_SQN   149760      /* 32768 f32 */
#define WS_X     281088      /* M*96 bf16 */
#define WS_Z1    25447424    /* M*144 bf16 (reused as Z3 [M][128]) */
#define WS_ZSC   63196416    /* M*128 bf16 */
#define WS_Z2    96751104    /* M*144 bf16; end ~134.5 MB */

extern "C" void kernel_launch(void* const* d_in, const int* in_sizes, int n_in,
                              void* d_out, int out_size, void* d_ws, size_t ws_size,
                              hipStream_t stream)
{
    const float* xyz    = (const float*)d_in[0];
    const float* pts    = (const float*)d_in[1];
    const float* fc1_w  = (const float*)d_in[2];
    const float* bn1_g  = (const float*)d_in[4];
    const float* bn1_b  = (const float*)d_in[5];
    const float* fc2_w  = (const float*)d_in[6];
    const float* bn2_g  = (const float*)d_in[8];
    const float* bn2_b  = (const float*)d_in[9];
    const float* fc3_w  = (const float*)d_in[10];
    const float* bn3_g  = (const float*)d_in[12];
    const float* bn3_b  = (const float*)d_in[13];
    const float* sc_w   = (const float*)d_in[14];
    const float* scbn_g = (const float*)d_in[16];
    const float* scbn_b = (const float*)d_in[17];

    char* ws = (char*)d_ws;
    float* st = (float*)(ws + WS_STATS);
    float* bn1_sum = st + 0,    *bn1_sq = st + 136;
    float* bnsc_sum = st + 272, *bnsc_sq = st + 400;
    float* bn2_sum = st + 528,  *bn2_sq = st + 664;
    float* bn3_sum = st + 800,  *bn3_sq = st + 928;

    unsigned short* WT1 = (unsigned short*)(ws + WS_WT1);
    unsigned short* WT2 = (unsigned short*)(ws + WS_WT2);
    unsigned short* WT3 = (unsigned short*)(ws + WS_WT3);
    float* SQN = (float*)(ws + WS_SQN);
    unsigned short* X   = (unsigned short*)(ws + WS_X);
    unsigned short* Z1  = (unsigned short*)(ws + WS_Z1);
    unsigned short* ZSC = (unsigned short*)(ws + WS_ZSC);
    unsigned short* Z2  = (unsigned short*)(ws + WS_Z2);
    unsigned short* Z3  = Z1;   // Z1 dead after gemm_l2
    float* out = (float*)d_out;

    hipMemsetAsync(ws + WS_STATS, 0, 1056 * 4, stream);

    fps_aux_kernel<<<48, 256, 0, stream>>>(xyz, out, fc1_w, sc_w, fc2_w, fc3_w,
                                           WT1, WT2, WT3, SQN);
    knn_build<<<2048, 256, 0, stream>>>(xyz, SQN, out, pts, X);

    gemm1_fused<<<2048, 256, 0, stream>>>(X, WT1, Z1, ZSC,
                                          bn1_sum, bn1_sq, bnsc_sum, bnsc_sq);
    gemm_l2<<<1024, 256, 0, stream>>>(Z1, WT2, Z2, bn2_sum, bn2_sq,
                                      bn1_sum, bn1_sq, bn1_g, bn1_b);
    gemm_l3<<<1024, 256, 0, stream>>>(Z2, WT3, Z3, bn3_sum, bn3_sq,
                                      bn2_sum, bn2_sq, bn2_g, bn2_b);

    final_kernel<<<512, 256, 0, stream>>>(Z3, ZSC, bn3_sum, bn3_sq, bn3_g, bn3_b,
                                          bnsc_sum, bnsc_sq, scbn_g, scbn_b, out);
}